// Round 4
// baseline (1221.689 us; speedup 1.0000x reference)
//
#include <hip/hip_runtime.h>
#include <cstdint>
#include <cstddef>

#define D 128

// ---------------------------------------------------------------------------
// histogram: counts[dst]++ (int atomics)
__global__ void hist_kernel(const int* __restrict__ dst, int E,
                            int* __restrict__ counts) {
    int i = blockIdx.x * blockDim.x + threadIdx.x;
    if (i < E) atomicAdd(&counts[dst[i]], 1);
}

// per-block sums of counts (for deterministic scan)
__global__ void block_sum_kernel(const int* __restrict__ counts, int n,
                                 int* __restrict__ bsum) {
    __shared__ int sh[256];
    int t = threadIdx.x;
    int i = blockIdx.x * 256 + t;
    sh[t] = (i < n) ? counts[i] : 0;
    __syncthreads();
    for (int off = 128; off; off >>= 1) {
        if (t < off) sh[t] += sh[t + off];
        __syncthreads();
    }
    if (t == 0) bsum[blockIdx.x] = sh[0];
}

// single-block LDS exclusive scan of bsum (nb <= 512); replaces the serial
// 1-thread scan (391 dependent global round-trips ~ tens of us).
__global__ void scan_small_kernel(int* __restrict__ bsum, int nb,
                                  int* __restrict__ row_ptr, int N, int E) {
    __shared__ int sh[512];
    int t = threadIdx.x;
    int v = (t < nb) ? bsum[t] : 0;
    sh[t] = v;
    __syncthreads();
    for (int off = 1; off < 512; off <<= 1) {
        int add = (t >= off) ? sh[t - off] : 0;
        __syncthreads();
        sh[t] += add;
        __syncthreads();
    }
    if (t < nb) bsum[t] = sh[t] - v;  // exclusive
    if (t == 0) row_ptr[N] = E;
}

// per-block exclusive scan + block offset -> row_ptr
__global__ void block_scan_kernel(const int* __restrict__ counts, int n,
                                  const int* __restrict__ bsum,
                                  int* __restrict__ row_ptr) {
    __shared__ int sh[256];
    int t = threadIdx.x;
    int i = blockIdx.x * 256 + t;
    int v = (i < n) ? counts[i] : 0;
    sh[t] = v;
    __syncthreads();
    for (int off = 1; off < 256; off <<= 1) {
        int add = (t >= off) ? sh[t - off] : 0;
        __syncthreads();
        sh[t] += add;
        __syncthreads();
    }
    if (i < n) row_ptr[i] = bsum[blockIdx.x] + sh[t] - v;
}

// place each edge's src into its dst bucket
__global__ void fill_kernel(const int* __restrict__ src,
                            const int* __restrict__ dst, int E,
                            const int* __restrict__ row_ptr,
                            int* __restrict__ cursor,
                            int* __restrict__ csr_src) {
    int i = blockIdx.x * blockDim.x + threadIdx.x;
    if (i < E) {
        int d = dst[i];
        int pos = row_ptr[d] + atomicAdd(&cursor[d], 1);
        csr_src[pos] = src[i];
    }
}

// ---------------------------------------------------------------------------
// Fused per-layer kernel: block = 256 threads = 64 output rows.
// Phase 1: gather-mean 64 nodes' neighbor rows into LDS AggT[64][132].
// Phase 2: hout = act( AggT @ Wn + h @ Ws + b [+ h] ), A-half1 read directly
//          from AggT (2 addrs/wave -> broadcast), h chunks staged into AggT's
//          dead alias space for half2, W staged per BK=32 chunk.
template <bool RELU, bool RES>
__global__ __launch_bounds__(256) void sage_layer(
    const float* __restrict__ h,        // [N, D] input features
    const int* __restrict__ row_ptr,    // [N+1]
    const int* __restrict__ csr_src,    // [E]
    const float* __restrict__ wn,       // [D, D] row-major (k, n)
    const float* __restrict__ wsf,      // [D, D]
    const float* __restrict__ bias,     // [D]
    float* __restrict__ hout, int N) {
    constexpr int PAD = 132;                 // row stride, 16B-aligned
    __shared__ float AggT[64 * PAD];         // 33792 B (alias: As2[64][32] in half2)
    __shared__ float Wt[32 * PAD];           // 16896 B, padded rows
    const int t = threadIdx.x;
    const int row0 = blockIdx.x * 64;

    // ---- phase 1: aggregate (one wave per node, 16 nodes per wave)
    {
        const int wv = t >> 6;
        const int lane = t & 63;
        const int col = lane * 2;
        for (int r = wv * 16; r < wv * 16 + 16; ++r) {
            int node = row0 + r;
            if (node >= N) break;                 // wave-uniform
            int beg = row_ptr[node], end = row_ptr[node + 1];
            float2 a0{0.f, 0.f}, a1{0.f, 0.f}, a2{0.f, 0.f}, a3{0.f, 0.f};
            int e = beg;
            for (; e + 4 <= end; e += 4) {
                int s0 = csr_src[e + 0], s1 = csr_src[e + 1];
                int s2 = csr_src[e + 2], s3 = csr_src[e + 3];
                float2 v0 = *(const float2*)(h + (size_t)s0 * D + col);
                float2 v1 = *(const float2*)(h + (size_t)s1 * D + col);
                float2 v2 = *(const float2*)(h + (size_t)s2 * D + col);
                float2 v3 = *(const float2*)(h + (size_t)s3 * D + col);
                a0.x += v0.x; a0.y += v0.y;
                a1.x += v1.x; a1.y += v1.y;
                a2.x += v2.x; a2.y += v2.y;
                a3.x += v3.x; a3.y += v3.y;
            }
            for (; e < end; ++e) {
                int s = csr_src[e];
                float2 v = *(const float2*)(h + (size_t)s * D + col);
                a0.x += v.x; a0.y += v.y;
            }
            float sc = 1.0f / fmaxf((float)(end - beg), 1.0f);
            float2 o;
            o.x = (a0.x + a1.x + a2.x + a3.x) * sc;
            o.y = (a0.y + a1.y + a2.y + a3.y) * sc;
            *(float2*)&AggT[r * PAD + col] = o;
        }
    }

    // ---- phase 2: GEMM
    const int rg = t >> 5;          // 0..7
    const int cg = t & 31;          // 0..31
    int lrow = row0 + (t >> 2);     // h-stage row (half2)
    if (lrow >= N) lrow = N - 1;    // clamp; results for clamped rows discarded
    const int acol = (t & 3) * 8;   // 8 floats per thread
    const int wrow = t >> 3;        // 0..31
    const int wcol = (t & 7) * 16;  // 16 floats per thread

    float acc[8][4];
#pragma unroll
    for (int i = 0; i < 8; i++)
#pragma unroll
        for (int j = 0; j < 4; j++) acc[i][j] = 0.0f;

    // half 1: A = AggT (LDS-resident), W = wn
    for (int kb = 0; kb < 128; kb += 32) {
        __syncthreads();   // phase-1 done (iter 0) / prev Wt reads done
        {
            const float* Wp = wn + (size_t)(kb + wrow) * D + wcol;
            float4 w0 = *(const float4*)(Wp + 0);
            float4 w1 = *(const float4*)(Wp + 4);
            float4 w2 = *(const float4*)(Wp + 8);
            float4 w3 = *(const float4*)(Wp + 12);
            float* wdst = &Wt[wrow * PAD + wcol];
            *(float4*)(wdst + 0)  = w0;
            *(float4*)(wdst + 4)  = w1;
            *(float4*)(wdst + 8)  = w2;
            *(float4*)(wdst + 12) = w3;
        }
        __syncthreads();
#pragma unroll
        for (int k4 = 0; k4 < 32; k4 += 4) {
            float4 a4[8];
#pragma unroll
            for (int i = 0; i < 8; i++)
                a4[i] = *(const float4*)&AggT[(rg * 8 + i) * PAD + kb + k4];
#pragma unroll
            for (int kk = 0; kk < 4; kk++) {
                float4 wvv = *(const float4*)&Wt[(k4 + kk) * PAD + cg * 4];
#pragma unroll
                for (int i = 0; i < 8; i++) {
                    const float av = ((const float*)&a4[i])[kk];
                    acc[i][0] = fmaf(av, wvv.x, acc[i][0]);
                    acc[i][1] = fmaf(av, wvv.y, acc[i][1]);
                    acc[i][2] = fmaf(av, wvv.z, acc[i][2]);
                    acc[i][3] = fmaf(av, wvv.w, acc[i][3]);
                }
            }
        }
    }

    // half 2: A = h chunks (staged into AggT alias space), W = wsf
    float* As2 = AggT;  // [64][32], stride 32
    for (int kb = 0; kb < 128; kb += 32) {
        __syncthreads();   // half-1 reads of AggT / prev iter reads done
        {
            const float* Ap = h + (size_t)lrow * D + kb + acol;
            float4 x0 = *(const float4*)(Ap + 0);
            float4 x1 = *(const float4*)(Ap + 4);
            float* adst = &As2[(t >> 2) * 32 + acol];
            *(float4*)(adst + 0) = x0;
            *(float4*)(adst + 4) = x1;
        }
        {
            const float* Wp = wsf + (size_t)(kb + wrow) * D + wcol;
            float4 w0 = *(const float4*)(Wp + 0);
            float4 w1 = *(const float4*)(Wp + 4);
            float4 w2 = *(const float4*)(Wp + 8);
            float4 w3 = *(const float4*)(Wp + 12);
            float* wdst = &Wt[wrow * PAD + wcol];
            *(float4*)(wdst + 0)  = w0;
            *(float4*)(wdst + 4)  = w1;
            *(float4*)(wdst + 8)  = w2;
            *(float4*)(wdst + 12) = w3;
        }
        __syncthreads();
#pragma unroll
        for (int k4 = 0; k4 < 32; k4 += 4) {
            float4 a4[8];
#pragma unroll
            for (int i = 0; i < 8; i++)
                a4[i] = *(const float4*)&As2[(rg * 8 + i) * 32 + k4];
#pragma unroll
            for (int kk = 0; kk < 4; kk++) {
                float4 wvv = *(const float4*)&Wt[(k4 + kk) * PAD + cg * 4];
#pragma unroll
                for (int i = 0; i < 8; i++) {
                    const float av = ((const float*)&a4[i])[kk];
                    acc[i][0] = fmaf(av, wvv.x, acc[i][0]);
                    acc[i][1] = fmaf(av, wvv.y, acc[i][1]);
                    acc[i][2] = fmaf(av, wvv.z, acc[i][2]);
                    acc[i][3] = fmaf(av, wvv.w, acc[i][3]);
                }
            }
        }
    }

    // epilogue
    const int col = cg * 4;
    const float4 bv = *(const float4*)(bias + col);
#pragma unroll
    for (int i = 0; i < 8; i++) {
        int row = row0 + rg * 8 + i;
        if (row >= N) continue;
        float4 o;
        o.x = acc[i][0] + bv.x;
        o.y = acc[i][1] + bv.y;
        o.z = acc[i][2] + bv.z;
        o.w = acc[i][3] + bv.w;
        if (RES) {
            float4 r = *(const float4*)(h + (size_t)row * D + col);
            o.x += r.x; o.y += r.y; o.z += r.z; o.w += r.w;
        }
        if (RELU) {
            o.x = fmaxf(o.x, 0.0f);
            o.y = fmaxf(o.y, 0.0f);
            o.z = fmaxf(o.z, 0.0f);
            o.w = fmaxf(o.w, 0.0f);
        }
        *(float4*)(hout + (size_t)row * D + col) = o;
    }
}

// ---------------------------------------------------------------------------
// logits[e] = dot(h[u], h[v])  (32 lanes per edge)
__global__ void decoder_kernel(const float* __restrict__ h,
                               const int* __restrict__ eli, int EL,
                               float* __restrict__ out) {
    long long tid = (long long)blockIdx.x * blockDim.x + threadIdx.x;
    int lane = (int)(tid & 31);
    long long e = tid >> 5;
    if (e >= EL) return;
    int u = eli[e];
    int v = eli[e + EL];
    float4 a = *(const float4*)(h + (long long)u * D + lane * 4);
    float4 b = *(const float4*)(h + (long long)v * D + lane * 4);
    float p = a.x * b.x + a.y * b.y + a.z * b.z + a.w * b.w;
#pragma unroll
    for (int off = 16; off; off >>= 1) p += __shfl_xor(p, off);
    if (lane == 0) out[e] = p;
}

// ---------------------------------------------------------------------------
static inline size_t align256(size_t x) { return (x + 255) & ~(size_t)255; }

extern "C" void kernel_launch(void* const* d_in, const int* in_sizes, int n_in,
                              void* d_out, int out_size, void* d_ws,
                              size_t ws_size, hipStream_t stream) {
    const float* x    = (const float*)d_in[0];   // [N, 128]
    const int*   ei   = (const int*)d_in[1];     // [2, E]
    const int*   eli  = (const int*)d_in[2];     // [2, EL]
    const float* wn   = (const float*)d_in[3];   // [3, 128, 128]
    const float* wsf  = (const float*)d_in[4];   // [3, 128, 128]
    const float* bias = (const float*)d_in[5];   // [3, 128]

    const int N  = in_sizes[0] / D;              // 100000
    const int E  = in_sizes[1] / 2;              // 1600000
    const int EL = in_sizes[2] / 2;              // 200000

    const int* src = ei;
    const int* dst = ei + E;

    // workspace layout
    char* p = (char*)d_ws;
    int*   counts  = (int*)p;   p += align256((size_t)N * sizeof(int));  // reused as cursor
    int*   row_ptr = (int*)p;   p += align256((size_t)(N + 1) * sizeof(int));
    int*   bsum    = (int*)p;   p += align256((size_t)1024 * sizeof(int));
    int*   csr_src = (int*)p;   p += align256((size_t)E * sizeof(int));
    float* hA      = (float*)p; p += align256((size_t)N * D * sizeof(float));
    float* hB      = (float*)p;

    const int nb = (N + 255) / 256;              // 391 (<= 512 for scan_small)
    const int eb = (E + 255) / 256;
    const int layer_blocks = (N + 63) / 64;

    // ---- CSR build (once; reused by all 3 layers)
    hipMemsetAsync(counts, 0, (size_t)N * sizeof(int), stream);
    hist_kernel<<<eb, 256, 0, stream>>>(dst, E, counts);
    block_sum_kernel<<<nb, 256, 0, stream>>>(counts, N, bsum);
    scan_small_kernel<<<1, 512, 0, stream>>>(bsum, nb, row_ptr, N, E);
    block_scan_kernel<<<nb, 256, 0, stream>>>(counts, N, bsum, row_ptr);
    hipMemsetAsync(counts, 0, (size_t)N * sizeof(int), stream);  // now cursor
    fill_kernel<<<eb, 256, 0, stream>>>(src, dst, E, row_ptr, counts, csr_src);

    // ---- fused layers
    sage_layer<true, false><<<layer_blocks, 256, 0, stream>>>(
        x, row_ptr, csr_src, wn + 0 * D * D, wsf + 0 * D * D, bias + 0 * D, hA, N);
    sage_layer<true, true><<<layer_blocks, 256, 0, stream>>>(
        hA, row_ptr, csr_src, wn + 1 * D * D, wsf + 1 * D * D, bias + 1 * D, hB, N);
    sage_layer<false, true><<<layer_blocks, 256, 0, stream>>>(
        hB, row_ptr, csr_src, wn + 2 * D * D, wsf + 2 * D * D, bias + 2 * D, hA, N);

    // ---- decoder
    decoder_kernel<<<(int)(((long long)EL * 32 + 255) / 256), 256, 0, stream>>>(
        hA, eli, EL, (float*)d_out);
}

// Round 6
// 885.706 us; speedup vs baseline: 1.3793x; 1.3793x over previous
//
#include <hip/hip_runtime.h>
#include <cstdint>
#include <cstddef>

#define D 128

typedef short short8 __attribute__((ext_vector_type(8)));
typedef float f32x4 __attribute__((ext_vector_type(4)));

static __device__ __forceinline__ unsigned short f2bf_rne(float f) {
    union { float f; uint32_t u; } v; v.f = f;
    uint32_t u = v.u + 0x7FFFu + ((v.u >> 16) & 1u);
    return (unsigned short)(u >> 16);
}
static __device__ __forceinline__ float bf2f(unsigned short h) {
    union { uint32_t u; float f; } v; v.u = ((uint32_t)h) << 16;
    return v.f;
}

// ---------------------------------------------------------------------------
// histogram: counts[dst]++ (int atomics)
__global__ void hist_kernel(const int* __restrict__ dst, int E,
                            int* __restrict__ counts) {
    int i = blockIdx.x * blockDim.x + threadIdx.x;
    if (i < E) atomicAdd(&counts[dst[i]], 1);
}

// per-block sums of counts (for deterministic scan)
__global__ void block_sum_kernel(const int* __restrict__ counts, int n,
                                 int* __restrict__ bsum) {
    __shared__ int sh[256];
    int t = threadIdx.x;
    int i = blockIdx.x * 256 + t;
    sh[t] = (i < n) ? counts[i] : 0;
    __syncthreads();
    for (int off = 128; off; off >>= 1) {
        if (t < off) sh[t] += sh[t + off];
        __syncthreads();
    }
    if (t == 0) bsum[blockIdx.x] = sh[0];
}

// single-block LDS exclusive scan of bsum (nb <= 512)
__global__ void scan_small_kernel(int* __restrict__ bsum, int nb,
                                  int* __restrict__ row_ptr, int N, int E) {
    __shared__ int sh[512];
    int t = threadIdx.x;
    int v = (t < nb) ? bsum[t] : 0;
    sh[t] = v;
    __syncthreads();
    for (int off = 1; off < 512; off <<= 1) {
        int add = (t >= off) ? sh[t - off] : 0;
        __syncthreads();
        sh[t] += add;
        __syncthreads();
    }
    if (t < nb) bsum[t] = sh[t] - v;  // exclusive
    if (t == 0) row_ptr[N] = E;
}

// per-block exclusive scan + block offset -> row_ptr
__global__ void block_scan_kernel(const int* __restrict__ counts, int n,
                                  const int* __restrict__ bsum,
                                  int* __restrict__ row_ptr) {
    __shared__ int sh[256];
    int t = threadIdx.x;
    int i = blockIdx.x * 256 + t;
    int v = (i < n) ? counts[i] : 0;
    sh[t] = v;
    __syncthreads();
    for (int off = 1; off < 256; off <<= 1) {
        int add = (t >= off) ? sh[t - off] : 0;
        __syncthreads();
        sh[t] += add;
        __syncthreads();
    }
    if (i < n) row_ptr[i] = bsum[blockIdx.x] + sh[t] - v;
}

// place each edge's src into its dst bucket
__global__ void fill_kernel(const int* __restrict__ src,
                            const int* __restrict__ dst, int E,
                            const int* __restrict__ row_ptr,
                            int* __restrict__ cursor,
                            int* __restrict__ csr_src) {
    int i = blockIdx.x * blockDim.x + threadIdx.x;
    if (i < E) {
        int d = dst[i];
        int pos = row_ptr[d] + atomicAdd(&cursor[d], 1);
        csr_src[pos] = src[i];
    }
}

// ---------------------------------------------------------------------------
// agg[node] = (1/deg) * sum_{e in CSR[node]} h[csr_src[e]]
__global__ __launch_bounds__(256) void gather_agg(
    const float* __restrict__ h, const int* __restrict__ row_ptr,
    const int* __restrict__ csr_src,
    float* __restrict__ agg, int N) {
    int node = (int)((blockIdx.x * (size_t)blockDim.x + threadIdx.x) >> 6);
    int lane = threadIdx.x & 63;
    if (node >= N) return;
    int beg = row_ptr[node], end = row_ptr[node + 1];
    const int col = lane * 2;
    float2 a0 = {0.f, 0.f}, a1 = {0.f, 0.f}, a2 = {0.f, 0.f}, a3 = {0.f, 0.f};
    int e = beg;
    for (; e + 4 <= end; e += 4) {
        int s0 = csr_src[e + 0];
        int s1 = csr_src[e + 1];
        int s2 = csr_src[e + 2];
        int s3 = csr_src[e + 3];
        float2 v0 = *(const float2*)(h + (size_t)s0 * D + col);
        float2 v1 = *(const float2*)(h + (size_t)s1 * D + col);
        float2 v2 = *(const float2*)(h + (size_t)s2 * D + col);
        float2 v3 = *(const float2*)(h + (size_t)s3 * D + col);
        a0.x += v0.x; a0.y += v0.y;
        a1.x += v1.x; a1.y += v1.y;
        a2.x += v2.x; a2.y += v2.y;
        a3.x += v3.x; a3.y += v3.y;
    }
    for (; e < end; ++e) {
        int s = csr_src[e];
        float2 v = *(const float2*)(h + (size_t)s * D + col);
        a0.x += v.x; a0.y += v.y;
    }
    float sc = 1.0f / fmaxf((float)(end - beg), 1.0f);
    float2 o;
    o.x = (a0.x + a1.x + a2.x + a3.x) * sc;
    o.y = (a0.y + a1.y + a2.y + a3.y) * sc;
    *(float2*)(agg + (size_t)node * D + col) = o;
}

// ---------------------------------------------------------------------------
// Weight prep: Wt[n][k] (256 k, k-major) split into bf16 hi/lo. 3 layers.
__global__ void wprep_kernel(const float* __restrict__ wn,
                             const float* __restrict__ wsf,
                             unsigned short* __restrict__ wth,
                             unsigned short* __restrict__ wtl) {
    int idx = blockIdx.x * 256 + threadIdx.x;   // 3*128*256 total
    int L = idx >> 15;
    int rem = idx & 32767;
    int n = rem >> 8;
    int k = rem & 255;
    float w = (k < 128) ? wn[L * 16384 + k * 128 + n]
                        : wsf[L * 16384 + (k - 128) * 128 + n];
    unsigned short hi = f2bf_rne(w);
    unsigned short lo = f2bf_rne(w - bf2f(hi));
    wth[idx] = hi;
    wtl[idx] = lo;
}

// ---------------------------------------------------------------------------
// Split-bf16 MFMA GEMM: hout = act( [agg|hin](N x 256) @ Wt^T + b [+ hin] ).
// Block: 64 rows x 128 cols, 4 waves, each wave 32m x 64n, 16x16x32 MFMA.
// LDS-free / barrier-free. Fragment maps (m89-verified): A row=lane&15,
// k=8*(lane>>4)+j; B col=lane&15, same k; D col=lane&15, row=4*(lane>>4)+reg.
template <bool RELU, bool RES>
__global__ __launch_bounds__(256) void gemm_mfma(
    const float* __restrict__ agg,           // [N, 128] (pre-scaled by 1/deg)
    const float* __restrict__ hin,           // [N, 128]
    const unsigned short* __restrict__ wth,  // [128 n][256 k] bf16 hi
    const unsigned short* __restrict__ wtl,  // [128 n][256 k] bf16 lo
    const float* __restrict__ bias,          // [128]
    float* __restrict__ hout, int N) {
    const int t = threadIdx.x;
    const int wv = t >> 6;
    const int lane = t & 63;
    const int r = lane & 15;
    const int q = lane >> 4;
    const int m0 = blockIdx.x * 64 + (wv >> 1) * 32;
    const int n0 = (wv & 1) * 64;

    int rowA0 = m0 + r;       if (rowA0 >= N) rowA0 = N - 1;
    int rowA1 = m0 + 16 + r;  if (rowA1 >= N) rowA1 = N - 1;

    f32x4 acc[2][4];
#pragma unroll
    for (int mt = 0; mt < 2; mt++)
#pragma unroll
        for (int nt = 0; nt < 4; nt++) acc[mt][nt] = (f32x4){0.f, 0.f, 0.f, 0.f};

#pragma unroll
    for (int kb = 0; kb < 8; kb++) {
        const float* base = (kb < 4) ? agg : hin;
        const int ko = (kb & 3) * 32 + q * 8;
        short8 ahi[2], alo[2];
#pragma unroll
        for (int mt = 0; mt < 2; mt++) {
            const float* p = base + (size_t)(mt ? rowA1 : rowA0) * D + ko;
            float4 f0 = *(const float4*)p;
            float4 f1 = *(const float4*)(p + 4);
            float a[8] = {f0.x, f0.y, f0.z, f0.w, f1.x, f1.y, f1.z, f1.w};
#pragma unroll
            for (int j = 0; j < 8; j++) {
                unsigned short h = f2bf_rne(a[j]);
                ahi[mt][j] = (short)h;
                alo[mt][j] = (short)f2bf_rne(a[j] - bf2f(h));
            }
        }
        const int wko = kb * 32 + q * 8;
#pragma unroll
        for (int nt = 0; nt < 4; nt++) {
            const size_t wo = (size_t)(n0 + nt * 16 + r) * 256 + wko;
            short8 wh = *(const short8*)(wth + wo);
            short8 wl = *(const short8*)(wtl + wo);
#pragma unroll
            for (int mt = 0; mt < 2; mt++) {
                acc[mt][nt] = __builtin_amdgcn_mfma_f32_16x16x32_bf16(
                    ahi[mt], wh, acc[mt][nt], 0, 0, 0);
                acc[mt][nt] = __builtin_amdgcn_mfma_f32_16x16x32_bf16(
                    alo[mt], wh, acc[mt][nt], 0, 0, 0);
                acc[mt][nt] = __builtin_amdgcn_mfma_f32_16x16x32_bf16(
                    ahi[mt], wl, acc[mt][nt], 0, 0, 0);
            }
        }
    }

    // epilogue: D col = n0+nt*16+r, row = m0+mt*16+q*4+reg
#pragma unroll
    for (int nt = 0; nt < 4; nt++) {
        const int col = n0 + nt * 16 + r;
        const float bv = bias[col];
#pragma unroll
        for (int mt = 0; mt < 2; mt++) {
#pragma unroll
            for (int reg = 0; reg < 4; reg++) {
                int row = m0 + mt * 16 + q * 4 + reg;
                if (row >= N) continue;
                float o = acc[mt][nt][reg] + bv;
                if (RES) o += hin[(size_t)row * D + col];
                if (RELU) o = fmaxf(o, 0.f);
                hout[(size_t)row * D + col] = o;
            }
        }
    }
}

// ---------------------------------------------------------------------------
// logits[e] = dot(h[u], h[v])  (32 lanes per edge)
__global__ void decoder_kernel(const float* __restrict__ h,
                               const int* __restrict__ eli, int EL,
                               float* __restrict__ out) {
    long long tid = (long long)blockIdx.x * blockDim.x + threadIdx.x;
    int lane = (int)(tid & 31);
    long long e = tid >> 5;
    if (e >= EL) return;
    int u = eli[e];
    int v = eli[e + EL];
    float4 a = *(const float4*)(h + (long long)u * D + lane * 4);
    float4 b = *(const float4*)(h + (long long)v * D + lane * 4);
    float p = a.x * b.x + a.y * b.y + a.z * b.z + a.w * b.w;
#pragma unroll
    for (int off = 16; off; off >>= 1) p += __shfl_xor(p, off);
    if (lane == 0) out[e] = p;
}

// ---------------------------------------------------------------------------
static inline size_t align256(size_t x) { return (x + 255) & ~(size_t)255; }

extern "C" void kernel_launch(void* const* d_in, const int* in_sizes, int n_in,
                              void* d_out, int out_size, void* d_ws,
                              size_t ws_size, hipStream_t stream) {
    const float* x    = (const float*)d_in[0];   // [N, 128]
    const int*   ei   = (const int*)d_in[1];     // [2, E]
    const int*   eli  = (const int*)d_in[2];     // [2, EL]
    const float* wn   = (const float*)d_in[3];   // [3, 128, 128]
    const float* wsf  = (const float*)d_in[4];   // [3, 128, 128]
    const float* bias = (const float*)d_in[5];   // [3, 128]

    const int N  = in_sizes[0] / D;              // 100000
    const int E  = in_sizes[1] / 2;              // 1600000
    const int EL = in_sizes[2] / 2;              // 200000

    const int* src = ei;
    const int* dst = ei + E;

    // workspace layout
    char* p = (char*)d_ws;
    int*   counts  = (int*)p;   p += align256((size_t)N * sizeof(int));  // reused as cursor
    int*   row_ptr = (int*)p;   p += align256((size_t)(N + 1) * sizeof(int));
    int*   bsum    = (int*)p;   p += align256((size_t)1024 * sizeof(int));
    unsigned short* wth = (unsigned short*)p; p += align256((size_t)3 * 32768 * 2);
    unsigned short* wtl = (unsigned short*)p; p += align256((size_t)3 * 32768 * 2);
    int*   csr_src = (int*)p;   p += align256((size_t)E * sizeof(int));
    float* agg     = (float*)p; p += align256((size_t)N * D * sizeof(float));
    float* hA      = (float*)p; p += align256((size_t)N * D * sizeof(float));
    float* hB      = (float*)p;

    const int nb = (N + 255) / 256;              // 391 (<= 512 for scan_small)
    const int eb = (E + 255) / 256;
    const int tile_blocks = (N + 63) / 64;
    const int gather_blocks = (N + 3) / 4;

    // ---- weight prep (3 layers at once)
    wprep_kernel<<<384, 256, 0, stream>>>(wn, wsf, wth, wtl);

    // ---- CSR build (once; reused by all 3 layers)
    hipMemsetAsync(counts, 0, (size_t)N * sizeof(int), stream);
    hist_kernel<<<eb, 256, 0, stream>>>(dst, E, counts);
    block_sum_kernel<<<nb, 256, 0, stream>>>(counts, N, bsum);
    scan_small_kernel<<<1, 512, 0, stream>>>(bsum, nb, row_ptr, N, E);
    block_scan_kernel<<<nb, 256, 0, stream>>>(counts, N, bsum, row_ptr);
    hipMemsetAsync(counts, 0, (size_t)N * sizeof(int), stream);  // now cursor
    fill_kernel<<<eb, 256, 0, stream>>>(src, dst, E, row_ptr, counts, csr_src);

    // ---- layer 0: relu(conv(x)) -> hA
    gather_agg<<<gather_blocks, 256, 0, stream>>>(x, row_ptr, csr_src, agg, N);
    gemm_mfma<true, false><<<tile_blocks, 256, 0, stream>>>(
        agg, x, wth + 0 * 32768, wtl + 0 * 32768, bias + 0 * D, hA, N);

    // ---- layer 1: relu(conv(hA) + hA) -> hB
    gather_agg<<<gather_blocks, 256, 0, stream>>>(hA, row_ptr, csr_src, agg, N);
    gemm_mfma<true, true><<<tile_blocks, 256, 0, stream>>>(
        agg, hA, wth + 1 * 32768, wtl + 1 * 32768, bias + 1 * D, hB, N);

    // ---- layer 2: conv(hB) + hB -> hA
    gather_agg<<<gather_blocks, 256, 0, stream>>>(hB, row_ptr, csr_src, agg, N);
    gemm_mfma<false, true><<<tile_blocks, 256, 0, stream>>>(
        agg, hB, wth + 2 * 32768, wtl + 2 * 32768, bias + 2 * D, hA, N);

    // ---- decoder
    decoder_kernel<<<(int)(((long long)EL * 32 + 255) / 256), 256, 0, stream>>>(
        hA, eli, EL, (float*)d_out);
}

// Round 7
// 749.458 us; speedup vs baseline: 1.6301x; 1.1818x over previous
//
#include <hip/hip_runtime.h>
#include <cstdint>
#include <cstddef>

#define D 128

typedef _Float16 half8 __attribute__((ext_vector_type(8)));
typedef float f32x4 __attribute__((ext_vector_type(4)));

static __device__ __forceinline__ unsigned short f2h_bits(float f) {
    union { _Float16 h; unsigned short u; } c;
    c.h = (_Float16)f;
    return c.u;
}

// ---------------------------------------------------------------------------
// histogram: counts[dst]++ (int atomics)
__global__ void hist_kernel(const int* __restrict__ dst, int E,
                            int* __restrict__ counts) {
    int i = blockIdx.x * blockDim.x + threadIdx.x;
    if (i < E) atomicAdd(&counts[dst[i]], 1);
}

// per-block sums of counts (for deterministic scan)
__global__ void block_sum_kernel(const int* __restrict__ counts, int n,
                                 int* __restrict__ bsum) {
    __shared__ int sh[256];
    int t = threadIdx.x;
    int i = blockIdx.x * 256 + t;
    sh[t] = (i < n) ? counts[i] : 0;
    __syncthreads();
    for (int off = 128; off; off >>= 1) {
        if (t < off) sh[t] += sh[t + off];
        __syncthreads();
    }
    if (t == 0) bsum[blockIdx.x] = sh[0];
}

// single-block LDS exclusive scan of bsum (nb <= 512)
__global__ void scan_small_kernel(int* __restrict__ bsum, int nb,
                                  int* __restrict__ row_ptr, int N, int E) {
    __shared__ int sh[512];
    int t = threadIdx.x;
    int v = (t < nb) ? bsum[t] : 0;
    sh[t] = v;
    __syncthreads();
    for (int off = 1; off < 512; off <<= 1) {
        int add = (t >= off) ? sh[t - off] : 0;
        __syncthreads();
        sh[t] += add;
        __syncthreads();
    }
    if (t < nb) bsum[t] = sh[t] - v;  // exclusive
    if (t == 0) row_ptr[N] = E;
}

// per-block exclusive scan + block offset -> row_ptr
__global__ void block_scan_kernel(const int* __restrict__ counts, int n,
                                  const int* __restrict__ bsum,
                                  int* __restrict__ row_ptr) {
    __shared__ int sh[256];
    int t = threadIdx.x;
    int i = blockIdx.x * 256 + t;
    int v = (i < n) ? counts[i] : 0;
    sh[t] = v;
    __syncthreads();
    for (int off = 1; off < 256; off <<= 1) {
        int add = (t >= off) ? sh[t - off] : 0;
        __syncthreads();
        sh[t] += add;
        __syncthreads();
    }
    if (i < n) row_ptr[i] = bsum[blockIdx.x] + sh[t] - v;
}

// place each edge's src into its dst bucket
__global__ void fill_kernel(const int* __restrict__ src,
                            const int* __restrict__ dst, int E,
                            const int* __restrict__ row_ptr,
                            int* __restrict__ cursor,
                            int* __restrict__ csr_src) {
    int i = blockIdx.x * blockDim.x + threadIdx.x;
    if (i < E) {
        int d = dst[i];
        int pos = row_ptr[d] + atomicAdd(&cursor[d], 1);
        csr_src[pos] = src[i];
    }
}

// ---------------------------------------------------------------------------
// fp32 -> fp16 copy (8 elems/thread)
__global__ void f32_to_f16(const float* __restrict__ in,
                           unsigned short* __restrict__ out, int n8) {
    int i = blockIdx.x * 256 + threadIdx.x;
    if (i >= n8) return;
    float4 f0 = ((const float4*)in)[2 * i];
    float4 f1 = ((const float4*)in)[2 * i + 1];
    union { unsigned short u[8]; uint4 v; } o;
    o.u[0] = f2h_bits(f0.x); o.u[1] = f2h_bits(f0.y);
    o.u[2] = f2h_bits(f0.z); o.u[3] = f2h_bits(f0.w);
    o.u[4] = f2h_bits(f1.x); o.u[5] = f2h_bits(f1.y);
    o.u[6] = f2h_bits(f1.z); o.u[7] = f2h_bits(f1.w);
    ((uint4*)out)[i] = o.v;
}

// ---------------------------------------------------------------------------
// agg16[node] = fp16( (1/deg) * sum h16[csr_src[e]] )  (fp32 accumulation)
// one 64-lane wave per node, 2 fp16 (4 B) per lane, unroll 8
__global__ __launch_bounds__(256) void gather_agg16(
    const unsigned short* __restrict__ h16, const int* __restrict__ row_ptr,
    const int* __restrict__ csr_src,
    unsigned short* __restrict__ agg16, int N) {
    int node = (int)((blockIdx.x * (size_t)blockDim.x + threadIdx.x) >> 6);
    int lane = threadIdx.x & 63;
    if (node >= N) return;
    int beg = row_ptr[node], end = row_ptr[node + 1];
    const int col = lane * 2;
    float ax[8], ay[8];
#pragma unroll
    for (int j = 0; j < 8; j++) { ax[j] = 0.f; ay[j] = 0.f; }
    int e = beg;
    for (; e + 8 <= end; e += 8) {
        int s[8];
#pragma unroll
        for (int j = 0; j < 8; j++) s[j] = csr_src[e + j];
        unsigned int v[8];
#pragma unroll
        for (int j = 0; j < 8; j++)
            v[j] = *(const unsigned int*)(h16 + (size_t)s[j] * D + col);
#pragma unroll
        for (int j = 0; j < 8; j++) {
            union { unsigned int u; _Float16 h[2]; } c; c.u = v[j];
            ax[j] += (float)c.h[0];
            ay[j] += (float)c.h[1];
        }
    }
    for (; e < end; ++e) {
        int s = csr_src[e];
        union { unsigned int u; _Float16 h[2]; } c;
        c.u = *(const unsigned int*)(h16 + (size_t)s * D + col);
        ax[0] += (float)c.h[0];
        ay[0] += (float)c.h[1];
    }
    float sx = (ax[0] + ax[1]) + (ax[2] + ax[3]) + (ax[4] + ax[5]) + (ax[6] + ax[7]);
    float sy = (ay[0] + ay[1]) + (ay[2] + ay[3]) + (ay[4] + ay[5]) + (ay[6] + ay[7]);
    float sc = 1.0f / fmaxf((float)(end - beg), 1.0f);
    union { unsigned int u; _Float16 h[2]; } o;
    o.h[0] = (_Float16)(sx * sc);
    o.h[1] = (_Float16)(sy * sc);
    *(unsigned int*)(agg16 + (size_t)node * D + col) = o.u;
}

// ---------------------------------------------------------------------------
// Weight prep: Wt[n][k] (256 k, k-major) split into fp16 hi/lo. 3 layers.
__global__ void wprep_kernel(const float* __restrict__ wn,
                             const float* __restrict__ wsf,
                             unsigned short* __restrict__ wh,
                             unsigned short* __restrict__ wl) {
    int idx = blockIdx.x * 256 + threadIdx.x;   // 3*128*256 total
    int L = idx >> 15;
    int rem = idx & 32767;
    int n = rem >> 8;
    int k = rem & 255;
    float w = (k < 128) ? wn[L * 16384 + k * 128 + n]
                        : wsf[L * 16384 + (k - 128) * 128 + n];
    _Float16 hi = (_Float16)w;
    _Float16 lo = (_Float16)(w - (float)hi);
    union { _Float16 h; unsigned short u; } ch, cl;
    ch.h = hi; cl.h = lo;
    wh[idx] = ch.u;
    wl[idx] = cl.u;
}

// ---------------------------------------------------------------------------
// fp16 MFMA GEMM: hout = act( [agg16|h16](N x 256) @ (Wh+Wl)^T + b [+ hres] ).
// Block: 64 rows x 128 cols, 4 waves, each wave 32m x 64n, 16x16x32 f16 MFMA.
// A is fp16 -> direct half8 fragment loads, no conversion. W 2-term fp16 split.
// Fragment maps: A row=lane&15, k=8*(lane>>4)+j; B col=lane&15, same k;
// D col=lane&15, row=4*(lane>>4)+reg.
template <bool RELU, bool RES, bool W16OUT>
__global__ __launch_bounds__(256) void gemm_mfma16(
    const unsigned short* __restrict__ agg16,   // [N,128] fp16
    const unsigned short* __restrict__ h16self, // [N,128] fp16
    const float* __restrict__ hres,             // [N,128] fp32 residual
    const unsigned short* __restrict__ wh,      // [128 n][256 k] fp16 hi
    const unsigned short* __restrict__ wl,      // [128 n][256 k] fp16 lo
    const float* __restrict__ bias,             // [128]
    float* __restrict__ hout,                   // [N,128] fp32
    unsigned short* __restrict__ h16out,        // [N,128] fp16 shadow
    int N) {
    const int t = threadIdx.x;
    const int wv = t >> 6;
    const int lane = t & 63;
    const int r = lane & 15;
    const int q = lane >> 4;
    const int m0 = blockIdx.x * 64 + (wv >> 1) * 32;
    const int n0 = (wv & 1) * 64;

    int rowA0 = m0 + r;       if (rowA0 >= N) rowA0 = N - 1;
    int rowA1 = m0 + 16 + r;  if (rowA1 >= N) rowA1 = N - 1;

    f32x4 acc[2][4];
#pragma unroll
    for (int mt = 0; mt < 2; mt++)
#pragma unroll
        for (int nt = 0; nt < 4; nt++) acc[mt][nt] = (f32x4){0.f, 0.f, 0.f, 0.f};

#pragma unroll
    for (int kb = 0; kb < 8; kb++) {
        const unsigned short* base = (kb < 4) ? agg16 : h16self;
        const int ko = (kb & 3) * 32 + q * 8;
        half8 a[2];
        a[0] = *(const half8*)(base + (size_t)rowA0 * D + ko);
        a[1] = *(const half8*)(base + (size_t)rowA1 * D + ko);
        const int wko = kb * 32 + q * 8;
#pragma unroll
        for (int nt = 0; nt < 4; nt++) {
            const size_t wo = (size_t)(n0 + nt * 16 + r) * 256 + wko;
            half8 whv = *(const half8*)(wh + wo);
            half8 wlv = *(const half8*)(wl + wo);
#pragma unroll
            for (int mt = 0; mt < 2; mt++) {
                acc[mt][nt] = __builtin_amdgcn_mfma_f32_16x16x32_f16(
                    a[mt], whv, acc[mt][nt], 0, 0, 0);
                acc[mt][nt] = __builtin_amdgcn_mfma_f32_16x16x32_f16(
                    a[mt], wlv, acc[mt][nt], 0, 0, 0);
            }
        }
    }

    // epilogue: D col = n0+nt*16+r, row = m0+mt*16+q*4+reg
#pragma unroll
    for (int nt = 0; nt < 4; nt++) {
        const int col = n0 + nt * 16 + r;
        const float bv = bias[col];
#pragma unroll
        for (int mt = 0; mt < 2; mt++) {
#pragma unroll
            for (int reg = 0; reg < 4; reg++) {
                int row = m0 + mt * 16 + q * 4 + reg;
                if (row >= N) continue;
                float o = acc[mt][nt][reg] + bv;
                if (RES) o += hres[(size_t)row * D + col];
                if (RELU) o = fmaxf(o, 0.f);
                hout[(size_t)row * D + col] = o;
                if (W16OUT) h16out[(size_t)row * D + col] = f2h_bits(o);
            }
        }
    }
}

// ---------------------------------------------------------------------------
// logits[e] = dot(h[u], h[v])  (32 lanes per edge)
__global__ void decoder_kernel(const float* __restrict__ h,
                               const int* __restrict__ eli, int EL,
                               float* __restrict__ out) {
    long long tid = (long long)blockIdx.x * blockDim.x + threadIdx.x;
    int lane = (int)(tid & 31);
    long long e = tid >> 5;
    if (e >= EL) return;
    int u = eli[e];
    int v = eli[e + EL];
    float4 a = *(const float4*)(h + (long long)u * D + lane * 4);
    float4 b = *(const float4*)(h + (long long)v * D + lane * 4);
    float p = a.x * b.x + a.y * b.y + a.z * b.z + a.w * b.w;
#pragma unroll
    for (int off = 16; off; off >>= 1) p += __shfl_xor(p, off);
    if (lane == 0) out[e] = p;
}

// ---------------------------------------------------------------------------
static inline size_t align256(size_t x) { return (x + 255) & ~(size_t)255; }

extern "C" void kernel_launch(void* const* d_in, const int* in_sizes, int n_in,
                              void* d_out, int out_size, void* d_ws,
                              size_t ws_size, hipStream_t stream) {
    const float* x    = (const float*)d_in[0];   // [N, 128]
    const int*   ei   = (const int*)d_in[1];     // [2, E]
    const int*   eli  = (const int*)d_in[2];     // [2, EL]
    const float* wn   = (const float*)d_in[3];   // [3, 128, 128]
    const float* wsf  = (const float*)d_in[4];   // [3, 128, 128]
    const float* bias = (const float*)d_in[5];   // [3, 128]

    const int N  = in_sizes[0] / D;              // 100000
    const int E  = in_sizes[1] / 2;              // 1600000
    const int EL = in_sizes[2] / 2;              // 200000

    const int* src = ei;
    const int* dst = ei + E;

    // workspace layout (~187 MB)
    char* p = (char*)d_ws;
    int*   counts  = (int*)p;   p += align256((size_t)N * sizeof(int));  // reused as cursor
    int*   row_ptr = (int*)p;   p += align256((size_t)(N + 1) * sizeof(int));
    int*   bsum    = (int*)p;   p += align256((size_t)1024 * sizeof(int));
    unsigned short* wh  = (unsigned short*)p; p += align256((size_t)3 * 32768 * 2);
    unsigned short* wl  = (unsigned short*)p; p += align256((size_t)3 * 32768 * 2);
    int*   csr_src = (int*)p;   p += align256((size_t)E * sizeof(int));
    unsigned short* x16   = (unsigned short*)p; p += align256((size_t)N * D * 2);  // also layer-2 shadow
    unsigned short* hA16  = (unsigned short*)p; p += align256((size_t)N * D * 2);
    unsigned short* agg16 = (unsigned short*)p; p += align256((size_t)N * D * 2);
    float* hA      = (float*)p; p += align256((size_t)N * D * sizeof(float));
    float* hB      = (float*)p;

    const int nb = (N + 255) / 256;              // 391 (<= 512 for scan_small)
    const int eb = (E + 255) / 256;
    const int tile_blocks = (N + 63) / 64;
    const int gather_blocks = (N + 3) / 4;
    const int n8 = N * D / 8;

    // ---- weight prep + fp16 copy of x
    wprep_kernel<<<384, 256, 0, stream>>>(wn, wsf, wh, wl);
    f32_to_f16<<<(n8 + 255) / 256, 256, 0, stream>>>(x, x16, n8);

    // ---- CSR build (once; reused by all 3 layers)
    hipMemsetAsync(counts, 0, (size_t)N * sizeof(int), stream);
    hist_kernel<<<eb, 256, 0, stream>>>(dst, E, counts);
    block_sum_kernel<<<nb, 256, 0, stream>>>(counts, N, bsum);
    scan_small_kernel<<<1, 512, 0, stream>>>(bsum, nb, row_ptr, N, E);
    block_scan_kernel<<<nb, 256, 0, stream>>>(counts, N, bsum, row_ptr);
    hipMemsetAsync(counts, 0, (size_t)N * sizeof(int), stream);  // now cursor
    fill_kernel<<<eb, 256, 0, stream>>>(src, dst, E, row_ptr, counts, csr_src);

    // ---- layer 0: relu(conv(x)) -> hA (fp32) + hA16 (fp16)
    gather_agg16<<<gather_blocks, 256, 0, stream>>>(x16, row_ptr, csr_src, agg16, N);
    gemm_mfma16<true, false, true><<<tile_blocks, 256, 0, stream>>>(
        agg16, x16, x, wh + 0 * 32768, wl + 0 * 32768, bias + 0 * D, hA, hA16, N);

    // ---- layer 1: relu(conv(hA) + hA) -> hB (fp32) + x16 (fp16, reused)
    gather_agg16<<<gather_blocks, 256, 0, stream>>>(hA16, row_ptr, csr_src, agg16, N);
    gemm_mfma16<true, true, true><<<tile_blocks, 256, 0, stream>>>(
        agg16, hA16, hA, wh + 1 * 32768, wl + 1 * 32768, bias + 1 * D, hB, x16, N);

    // ---- layer 2: conv(hB) + hB -> hA (fp32 only)
    gather_agg16<<<gather_blocks, 256, 0, stream>>>(x16, row_ptr, csr_src, agg16, N);
    gemm_mfma16<false, true, false><<<tile_blocks, 256, 0, stream>>>(
        agg16, x16, hB, wh + 2 * 32768, wl + 2 * 32768, bias + 2 * D, hA, nullptr, N);

    // ---- decoder
    decoder_kernel<<<(int)(((long long)EL * 32 + 255) / 256), 256, 0, stream>>>(
        hA, eli, EL, (float*)d_out);
}

// Round 8
// 715.057 us; speedup vs baseline: 1.7085x; 1.0481x over previous
//
#include <hip/hip_runtime.h>
#include <cstdint>
#include <cstddef>

#define D 128

typedef _Float16 half8 __attribute__((ext_vector_type(8)));
typedef float f32x4 __attribute__((ext_vector_type(4)));

static __device__ __forceinline__ unsigned short f2h_bits(float f) {
    union { _Float16 h; unsigned short u; } c;
    c.h = (_Float16)f;
    return c.u;
}

// ---------------------------------------------------------------------------
// histogram: counts[dst]++ (int atomics)
__global__ void hist_kernel(const int* __restrict__ dst, int E,
                            int* __restrict__ counts) {
    int i = blockIdx.x * blockDim.x + threadIdx.x;
    if (i < E) atomicAdd(&counts[dst[i]], 1);
}

// per-block sums of counts (for deterministic scan)
__global__ void block_sum_kernel(const int* __restrict__ counts, int n,
                                 int* __restrict__ bsum) {
    __shared__ int sh[256];
    int t = threadIdx.x;
    int i = blockIdx.x * 256 + t;
    sh[t] = (i < n) ? counts[i] : 0;
    __syncthreads();
    for (int off = 128; off; off >>= 1) {
        if (t < off) sh[t] += sh[t + off];
        __syncthreads();
    }
    if (t == 0) bsum[blockIdx.x] = sh[0];
}

// single-block LDS exclusive scan of bsum (nb <= 512)
__global__ void scan_small_kernel(int* __restrict__ bsum, int nb,
                                  int* __restrict__ row_ptr, int N, int E) {
    __shared__ int sh[512];
    int t = threadIdx.x;
    int v = (t < nb) ? bsum[t] : 0;
    sh[t] = v;
    __syncthreads();
    for (int off = 1; off < 512; off <<= 1) {
        int add = (t >= off) ? sh[t - off] : 0;
        __syncthreads();
        sh[t] += add;
        __syncthreads();
    }
    if (t < nb) bsum[t] = sh[t] - v;  // exclusive
    if (t == 0) row_ptr[N] = E;
}

// per-block exclusive scan + block offset -> row_ptr
__global__ void block_scan_kernel(const int* __restrict__ counts, int n,
                                  const int* __restrict__ bsum,
                                  int* __restrict__ row_ptr) {
    __shared__ int sh[256];
    int t = threadIdx.x;
    int i = blockIdx.x * 256 + t;
    int v = (i < n) ? counts[i] : 0;
    sh[t] = v;
    __syncthreads();
    for (int off = 1; off < 256; off <<= 1) {
        int add = (t >= off) ? sh[t - off] : 0;
        __syncthreads();
        sh[t] += add;
        __syncthreads();
    }
    if (i < n) row_ptr[i] = bsum[blockIdx.x] + sh[t] - v;
}

// place each edge's src into its dst bucket
__global__ void fill_kernel(const int* __restrict__ src,
                            const int* __restrict__ dst, int E,
                            const int* __restrict__ row_ptr,
                            int* __restrict__ cursor,
                            int* __restrict__ csr_src) {
    int i = blockIdx.x * blockDim.x + threadIdx.x;
    if (i < E) {
        int d = dst[i];
        int pos = row_ptr[d] + atomicAdd(&cursor[d], 1);
        csr_src[pos] = src[i];
    }
}

// ---------------------------------------------------------------------------
// fp32 -> fp16 copy (8 elems/thread)
__global__ void f32_to_f16(const float* __restrict__ in,
                           unsigned short* __restrict__ out, int n8) {
    int i = blockIdx.x * 256 + threadIdx.x;
    if (i >= n8) return;
    float4 f0 = ((const float4*)in)[2 * i];
    float4 f1 = ((const float4*)in)[2 * i + 1];
    union { unsigned short u[8]; uint4 v; } o;
    o.u[0] = f2h_bits(f0.x); o.u[1] = f2h_bits(f0.y);
    o.u[2] = f2h_bits(f0.z); o.u[3] = f2h_bits(f0.w);
    o.u[4] = f2h_bits(f1.x); o.u[5] = f2h_bits(f1.y);
    o.u[6] = f2h_bits(f1.z); o.u[7] = f2h_bits(f1.w);
    ((uint4*)out)[i] = o.v;
}

// ---------------------------------------------------------------------------
// agg16[node] = fp16( (1/deg) * sum h16[csr_src[e]] )  (fp32 accumulation)
// one 64-lane wave per node, 2 fp16 (4 B) per lane, unroll 8
__global__ __launch_bounds__(256) void gather_agg16(
    const unsigned short* __restrict__ h16, const int* __restrict__ row_ptr,
    const int* __restrict__ csr_src,
    unsigned short* __restrict__ agg16, int N) {
    int node = (int)((blockIdx.x * (size_t)blockDim.x + threadIdx.x) >> 6);
    int lane = threadIdx.x & 63;
    if (node >= N) return;
    int beg = row_ptr[node], end = row_ptr[node + 1];
    const int col = lane * 2;
    float ax[8], ay[8];
#pragma unroll
    for (int j = 0; j < 8; j++) { ax[j] = 0.f; ay[j] = 0.f; }
    int e = beg;
    for (; e + 8 <= end; e += 8) {
        int s[8];
#pragma unroll
        for (int j = 0; j < 8; j++) s[j] = csr_src[e + j];
        unsigned int v[8];
#pragma unroll
        for (int j = 0; j < 8; j++)
            v[j] = *(const unsigned int*)(h16 + (size_t)s[j] * D + col);
#pragma unroll
        for (int j = 0; j < 8; j++) {
            union { unsigned int u; _Float16 h[2]; } c; c.u = v[j];
            ax[j] += (float)c.h[0];
            ay[j] += (float)c.h[1];
        }
    }
    for (; e < end; ++e) {
        int s = csr_src[e];
        union { unsigned int u; _Float16 h[2]; } c;
        c.u = *(const unsigned int*)(h16 + (size_t)s * D + col);
        ax[0] += (float)c.h[0];
        ay[0] += (float)c.h[1];
    }
    float sx = (ax[0] + ax[1]) + (ax[2] + ax[3]) + (ax[4] + ax[5]) + (ax[6] + ax[7]);
    float sy = (ay[0] + ay[1]) + (ay[2] + ay[3]) + (ay[4] + ay[5]) + (ay[6] + ay[7]);
    float sc = 1.0f / fmaxf((float)(end - beg), 1.0f);
    union { unsigned int u; _Float16 h[2]; } o;
    o.h[0] = (_Float16)(sx * sc);
    o.h[1] = (_Float16)(sy * sc);
    *(unsigned int*)(agg16 + (size_t)node * D + col) = o.u;
}

// ---------------------------------------------------------------------------
// Weight prep: Wt[n][k] (256 k, k-major) split into fp16 hi/lo. 3 layers.
__global__ void wprep_kernel(const float* __restrict__ wn,
                             const float* __restrict__ wsf,
                             unsigned short* __restrict__ wh,
                             unsigned short* __restrict__ wl) {
    int idx = blockIdx.x * 256 + threadIdx.x;   // 3*128*256 total
    int L = idx >> 15;
    int rem = idx & 32767;
    int n = rem >> 8;
    int k = rem & 255;
    float w = (k < 128) ? wn[L * 16384 + k * 128 + n]
                        : wsf[L * 16384 + (k - 128) * 128 + n];
    _Float16 hi = (_Float16)w;
    _Float16 lo = (_Float16)(w - (float)hi);
    union { _Float16 h; unsigned short u; } ch, cl;
    ch.h = hi; cl.h = lo;
    wh[idx] = ch.u;
    wl[idx] = cl.u;
}

// ---------------------------------------------------------------------------
// fp16 MFMA GEMM: out = act( [agg16|h16self](N x 256) @ (Wh+Wl)^T + b [+ res16] )
// Block: 128 rows x 128 cols, 4 waves (2m x 2n), wave = 64m x 64n (mt=4,nt=4).
// 16x16x32 f16 MFMA, LDS-free / barrier-free; per kb: 12 loads -> 32 MFMAs.
// Layers 0/1 write fp16 shadow only; layer 2 writes fp32 only (F32OUT).
// Fragment maps: A row=lane&15, k=8*(lane>>4)+j; B col=lane&15, same k;
// D col=lane&15, row=4*(lane>>4)+reg.
template <bool RELU, bool RES, bool F32OUT>
__global__ __launch_bounds__(256) void gemm_mfma16(
    const unsigned short* __restrict__ agg16,   // [N,128] fp16
    const unsigned short* __restrict__ h16self, // [N,128] fp16
    const unsigned short* __restrict__ res16,   // [N,128] fp16 residual
    const unsigned short* __restrict__ wh,      // [128 n][256 k] fp16 hi
    const unsigned short* __restrict__ wl,      // [128 n][256 k] fp16 lo
    const float* __restrict__ bias,             // [128]
    float* __restrict__ hout,                   // [N,128] fp32 (F32OUT)
    unsigned short* __restrict__ h16out,        // [N,128] fp16 (!F32OUT)
    int N) {
    const int t = threadIdx.x;
    const int wv = t >> 6;
    const int lane = t & 63;
    const int r = lane & 15;
    const int q = lane >> 4;
    const int m0 = blockIdx.x * 128 + (wv >> 1) * 64;
    const int n0 = (wv & 1) * 64;

    int rowA[4];
#pragma unroll
    for (int mt = 0; mt < 4; mt++) {
        int rr = m0 + mt * 16 + r;
        rowA[mt] = (rr < N) ? rr : (N - 1);   // clamp; clamped results discarded
    }

    f32x4 acc[4][4];
#pragma unroll
    for (int mt = 0; mt < 4; mt++)
#pragma unroll
        for (int nt = 0; nt < 4; nt++) acc[mt][nt] = (f32x4){0.f, 0.f, 0.f, 0.f};

#pragma unroll
    for (int kb = 0; kb < 8; kb++) {
        const unsigned short* base = (kb < 4) ? agg16 : h16self;
        const int ko = (kb & 3) * 32 + q * 8;
        half8 a[4];
#pragma unroll
        for (int mt = 0; mt < 4; mt++)
            a[mt] = *(const half8*)(base + (size_t)rowA[mt] * D + ko);
        const int wko = kb * 32 + q * 8;
#pragma unroll
        for (int nt = 0; nt < 4; nt++) {
            const size_t wo = (size_t)(n0 + nt * 16 + r) * 256 + wko;
            half8 whv = *(const half8*)(wh + wo);
            half8 wlv = *(const half8*)(wl + wo);
#pragma unroll
            for (int mt = 0; mt < 4; mt++) {
                acc[mt][nt] = __builtin_amdgcn_mfma_f32_16x16x32_f16(
                    a[mt], whv, acc[mt][nt], 0, 0, 0);
                acc[mt][nt] = __builtin_amdgcn_mfma_f32_16x16x32_f16(
                    a[mt], wlv, acc[mt][nt], 0, 0, 0);
            }
        }
    }

    // epilogue: D col = n0+nt*16+r, row = m0+mt*16+q*4+reg
#pragma unroll
    for (int nt = 0; nt < 4; nt++) {
        const int col = n0 + nt * 16 + r;
        const float bv = bias[col];
#pragma unroll
        for (int mt = 0; mt < 4; mt++) {
#pragma unroll
            for (int reg = 0; reg < 4; reg++) {
                int row = m0 + mt * 16 + q * 4 + reg;
                if (row >= N) continue;
                float o = acc[mt][nt][reg] + bv;
                if (RES)
                    o += (float)(*(const _Float16*)(res16 + (size_t)row * D + col));
                if (RELU) o = fmaxf(o, 0.f);
                if (F32OUT) hout[(size_t)row * D + col] = o;
                else        h16out[(size_t)row * D + col] = f2h_bits(o);
            }
        }
    }
}

// ---------------------------------------------------------------------------
// logits[e] = dot(h[u], h[v])  (32 lanes per edge)
__global__ void decoder_kernel(const float* __restrict__ h,
                               const int* __restrict__ eli, int EL,
                               float* __restrict__ out) {
    long long tid = (long long)blockIdx.x * blockDim.x + threadIdx.x;
    int lane = (int)(tid & 31);
    long long e = tid >> 5;
    if (e >= EL) return;
    int u = eli[e];
    int v = eli[e + EL];
    float4 a = *(const float4*)(h + (long long)u * D + lane * 4);
    float4 b = *(const float4*)(h + (long long)v * D + lane * 4);
    float p = a.x * b.x + a.y * b.y + a.z * b.z + a.w * b.w;
#pragma unroll
    for (int off = 16; off; off >>= 1) p += __shfl_xor(p, off);
    if (lane == 0) out[e] = p;
}

// ---------------------------------------------------------------------------
static inline size_t align256(size_t x) { return (x + 255) & ~(size_t)255; }

extern "C" void kernel_launch(void* const* d_in, const int* in_sizes, int n_in,
                              void* d_out, int out_size, void* d_ws,
                              size_t ws_size, hipStream_t stream) {
    const float* x    = (const float*)d_in[0];   // [N, 128]
    const int*   ei   = (const int*)d_in[1];     // [2, E]
    const int*   eli  = (const int*)d_in[2];     // [2, EL]
    const float* wn   = (const float*)d_in[3];   // [3, 128, 128]
    const float* wsf  = (const float*)d_in[4];   // [3, 128, 128]
    const float* bias = (const float*)d_in[5];   // [3, 128]

    const int N  = in_sizes[0] / D;              // 100000
    const int E  = in_sizes[1] / 2;              // 1600000
    const int EL = in_sizes[2] / 2;              // 200000

    const int* src = ei;
    const int* dst = ei + E;

    // workspace layout (~160 MB)
    char* p = (char*)d_ws;
    int*   counts  = (int*)p;   p += align256((size_t)N * sizeof(int));  // reused as cursor
    int*   row_ptr = (int*)p;   p += align256((size_t)(N + 1) * sizeof(int));
    int*   bsum    = (int*)p;   p += align256((size_t)1024 * sizeof(int));
    unsigned short* wh  = (unsigned short*)p; p += align256((size_t)3 * 32768 * 2);
    unsigned short* wl  = (unsigned short*)p; p += align256((size_t)3 * 32768 * 2);
    int*   csr_src = (int*)p;   p += align256((size_t)E * sizeof(int));
    unsigned short* x16   = (unsigned short*)p; p += align256((size_t)N * D * 2);
    unsigned short* h1    = (unsigned short*)p; p += align256((size_t)N * D * 2);
    unsigned short* h2    = (unsigned short*)p; p += align256((size_t)N * D * 2);
    unsigned short* agg16 = (unsigned short*)p; p += align256((size_t)N * D * 2);
    float* hA      = (float*)p;  // fp32 final (decoder input)

    const int nb = (N + 255) / 256;              // 391 (<= 512 for scan_small)
    const int eb = (E + 255) / 256;
    const int tile_blocks = (N + 127) / 128;     // 782
    const int gather_blocks = (N + 3) / 4;
    const int n8 = N * D / 8;

    // ---- weight prep + fp16 copy of x
    wprep_kernel<<<384, 256, 0, stream>>>(wn, wsf, wh, wl);
    f32_to_f16<<<(n8 + 255) / 256, 256, 0, stream>>>(x, x16, n8);

    // ---- CSR build (once; reused by all 3 layers)
    hipMemsetAsync(counts, 0, (size_t)N * sizeof(int), stream);
    hist_kernel<<<eb, 256, 0, stream>>>(dst, E, counts);
    block_sum_kernel<<<nb, 256, 0, stream>>>(counts, N, bsum);
    scan_small_kernel<<<1, 512, 0, stream>>>(bsum, nb, row_ptr, N, E);
    block_scan_kernel<<<nb, 256, 0, stream>>>(counts, N, bsum, row_ptr);
    hipMemsetAsync(counts, 0, (size_t)N * sizeof(int), stream);  // now cursor
    fill_kernel<<<eb, 256, 0, stream>>>(src, dst, E, row_ptr, counts, csr_src);

    // ---- layer 0: relu(conv(x)) -> h1 (fp16 only)
    gather_agg16<<<gather_blocks, 256, 0, stream>>>(x16, row_ptr, csr_src, agg16, N);
    gemm_mfma16<true, false, false><<<tile_blocks, 256, 0, stream>>>(
        agg16, x16, nullptr, wh + 0 * 32768, wl + 0 * 32768, bias + 0 * D,
        nullptr, h1, N);

    // ---- layer 1: relu(conv(h1) + h1) -> h2 (fp16 only)
    gather_agg16<<<gather_blocks, 256, 0, stream>>>(h1, row_ptr, csr_src, agg16, N);
    gemm_mfma16<true, true, false><<<tile_blocks, 256, 0, stream>>>(
        agg16, h1, h1, wh + 1 * 32768, wl + 1 * 32768, bias + 1 * D,
        nullptr, h2, N);

    // ---- layer 2: conv(h2) + h2 -> hA (fp32, decoder input)
    gather_agg16<<<gather_blocks, 256, 0, stream>>>(h2, row_ptr, csr_src, agg16, N);
    gemm_mfma16<false, true, true><<<tile_blocks, 256, 0, stream>>>(
        agg16, h2, h2, wh + 2 * 32768, wl + 2 * 32768, bias + 2 * D,
        hA, nullptr, N);

    // ---- decoder
    decoder_kernel<<<(int)(((long long)EL * 32 + 255) / 256), 256, 0, stream>>>(
        hA, eli, EL, (float*)d_out);
}

// Round 11
// 658.826 us; speedup vs baseline: 1.8543x; 1.0854x over previous
//
#include <hip/hip_runtime.h>
#include <cstdint>
#include <cstddef>

#define D 128

typedef _Float16 half8 __attribute__((ext_vector_type(8)));
typedef float f32x4 __attribute__((ext_vector_type(4)));

static __device__ __forceinline__ unsigned short f2h_bits(float f) {
    union { _Float16 h; unsigned short u; } c;
    c.h = (_Float16)f;
    return c.u;
}

// ---------------------------------------------------------------------------
// histogram: counts[dst]++ (int atomics)
__global__ void hist_kernel(const int* __restrict__ dst, int E,
                            int* __restrict__ counts) {
    int i = blockIdx.x * blockDim.x + threadIdx.x;
    if (i < E) atomicAdd(&counts[dst[i]], 1);
}

// per-block sums of counts (for deterministic scan)
__global__ void block_sum_kernel(const int* __restrict__ counts, int n,
                                 int* __restrict__ bsum) {
    __shared__ int sh[256];
    int t = threadIdx.x;
    int i = blockIdx.x * 256 + t;
    sh[t] = (i < n) ? counts[i] : 0;
    __syncthreads();
    for (int off = 128; off; off >>= 1) {
        if (t < off) sh[t] += sh[t + off];
        __syncthreads();
    }
    if (t == 0) bsum[blockIdx.x] = sh[0];
}

// single-block LDS exclusive scan of bsum (nb <= 512)
__global__ void scan_small_kernel(int* __restrict__ bsum, int nb,
                                  int* __restrict__ row_ptr, int N, int E) {
    __shared__ int sh[512];
    int t = threadIdx.x;
    int v = (t < nb) ? bsum[t] : 0;
    sh[t] = v;
    __syncthreads();
    for (int off = 1; off < 512; off <<= 1) {
        int add = (t >= off) ? sh[t - off] : 0;
        __syncthreads();
        sh[t] += add;
        __syncthreads();
    }
    if (t < nb) bsum[t] = sh[t] - v;  // exclusive
    if (t == 0) row_ptr[N] = E;
}

// per-block exclusive scan + block offset -> row_ptr
__global__ void block_scan_kernel(const int* __restrict__ counts, int n,
                                  const int* __restrict__ bsum,
                                  int* __restrict__ row_ptr) {
    __shared__ int sh[256];
    int t = threadIdx.x;
    int i = blockIdx.x * 256 + t;
    int v = (i < n) ? counts[i] : 0;
    sh[t] = v;
    __syncthreads();
    for (int off = 1; off < 256; off <<= 1) {
        int add = (t >= off) ? sh[t - off] : 0;
        __syncthreads();
        sh[t] += add;
        __syncthreads();
    }
    if (i < n) row_ptr[i] = bsum[blockIdx.x] + sh[t] - v;
}

// place each edge's src into its dst bucket; counts is consumed as a
// countdown cursor (old-1 = slot), so no re-zeroing memset is needed.
__global__ void fill_kernel(const int* __restrict__ src,
                            const int* __restrict__ dst, int E,
                            const int* __restrict__ row_ptr,
                            int* __restrict__ counts,
                            int* __restrict__ csr_src) {
    int i = blockIdx.x * blockDim.x + threadIdx.x;
    if (i < E) {
        int d = dst[i];
        int pos = row_ptr[d] + atomicSub(&counts[d], 1) - 1;
        csr_src[pos] = src[i];
    }
}

// ---------------------------------------------------------------------------
// fp32 -> fp16 copy (8 elems/thread)
__global__ void f32_to_f16(const float* __restrict__ in,
                           unsigned short* __restrict__ out, int n8) {
    int i = blockIdx.x * 256 + threadIdx.x;
    if (i >= n8) return;
    float4 f0 = ((const float4*)in)[2 * i];
    float4 f1 = ((const float4*)in)[2 * i + 1];
    union { unsigned short u[8]; uint4 v; } o;
    o.u[0] = f2h_bits(f0.x); o.u[1] = f2h_bits(f0.y);
    o.u[2] = f2h_bits(f0.z); o.u[3] = f2h_bits(f0.w);
    o.u[4] = f2h_bits(f1.x); o.u[5] = f2h_bits(f1.y);
    o.u[6] = f2h_bits(f1.z); o.u[7] = f2h_bits(f1.w);
    ((uint4*)out)[i] = o.v;
}

// ---------------------------------------------------------------------------
// agg16[node] = fp16( (1/deg) * sum h16[csr_src[e]] )  (fp32 accumulation)
// one 64-lane wave per node, 2 fp16 (4 B) per lane, unroll 8
__global__ __launch_bounds__(256) void gather_agg16(
    const unsigned short* __restrict__ h16, const int* __restrict__ row_ptr,
    const int* __restrict__ csr_src,
    unsigned short* __restrict__ agg16, int N) {
    int node = (int)((blockIdx.x * (size_t)blockDim.x + threadIdx.x) >> 6);
    int lane = threadIdx.x & 63;
    if (node >= N) return;
    int beg = row_ptr[node], end = row_ptr[node + 1];
    const int col = lane * 2;
    float ax[8], ay[8];
#pragma unroll
    for (int j = 0; j < 8; j++) { ax[j] = 0.f; ay[j] = 0.f; }
    int e = beg;
    for (; e + 8 <= end; e += 8) {
        int s[8];
#pragma unroll
        for (int j = 0; j < 8; j++) s[j] = csr_src[e + j];
        unsigned int v[8];
#pragma unroll
        for (int j = 0; j < 8; j++)
            v[j] = *(const unsigned int*)(h16 + (size_t)s[j] * D + col);
#pragma unroll
        for (int j = 0; j < 8; j++) {
            union { unsigned int u; _Float16 h[2]; } c; c.u = v[j];
            ax[j] += (float)c.h[0];
            ay[j] += (float)c.h[1];
        }
    }
    for (; e < end; ++e) {
        int s = csr_src[e];
        union { unsigned int u; _Float16 h[2]; } c;
        c.u = *(const unsigned int*)(h16 + (size_t)s * D + col);
        ax[0] += (float)c.h[0];
        ay[0] += (float)c.h[1];
    }
    float sx = (ax[0] + ax[1]) + (ax[2] + ax[3]) + (ax[4] + ax[5]) + (ax[6] + ax[7]);
    float sy = (ay[0] + ay[1]) + (ay[2] + ay[3]) + (ay[4] + ay[5]) + (ay[6] + ay[7]);
    float sc = 1.0f / fmaxf((float)(end - beg), 1.0f);
    union { unsigned int u; _Float16 h[2]; } o;
    o.h[0] = (_Float16)(sx * sc);
    o.h[1] = (_Float16)(sy * sc);
    *(unsigned int*)(agg16 + (size_t)node * D + col) = o.u;
}

// ---------------------------------------------------------------------------
// Weight prep, FRAGMENT-PACKED: element (L, nb, kb, lane, j) holds
// W[n = nb*16 + (lane&15)][k = kb*32 + (lane>>4)*8 + j], split fp16 hi/lo.
// A wave's W-fragment load is then whp + ((nb*8+kb)*64 + lane)*8 — one
// fully-coalesced 1 KB segment per wave-load (8 cache lines vs 32 scattered).
__global__ void wprep_kernel(const float* __restrict__ wn,
                             const float* __restrict__ wsf,
                             unsigned short* __restrict__ whp,
                             unsigned short* __restrict__ wlp) {
    int tid = blockIdx.x * 256 + threadIdx.x;   // [L][nb][kb][lane] = 12288
    if (tid >= 12288) return;
    int lane = tid & 63;
    int kb = (tid >> 6) & 7;
    int nb = (tid >> 9) & 7;
    int L  = tid >> 12;
    int n = nb * 16 + (lane & 15);
    int kbase = kb * 32 + (lane >> 4) * 8;
    union { unsigned short u[8]; uint4 v; } oh, ol;
#pragma unroll
    for (int j = 0; j < 8; j++) {
        int k = kbase + j;
        float w = (k < 128) ? wn[L * 16384 + k * 128 + n]
                            : wsf[L * 16384 + (k - 128) * 128 + n];
        _Float16 hi = (_Float16)w;
        _Float16 lo = (_Float16)(w - (float)hi);
        union { _Float16 h; unsigned short u; } ch, cl;
        ch.h = hi; cl.h = lo;
        oh.u[j] = ch.u;
        ol.u[j] = cl.u;
    }
    ((uint4*)whp)[tid] = oh.v;
    ((uint4*)wlp)[tid] = ol.v;
}

// ---------------------------------------------------------------------------
// fp16 MFMA GEMM, software-pipelined (1-ahead A/W prefetch), packed W.
// Block: 128 rows x 128 cols, 4 waves (2m x 2n), wave = 64m x 64n (mt=4,nt=4).
// 16x16x32 f16 MFMA, LDS-free / barrier-free; per kb: 12 loads -> 32 MFMAs.
// Fragment maps: A row=lane&15, k=8*(lane>>4)+j; B col=lane&15, same k;
// D col=lane&15, row=4*(lane>>4)+reg.
template <bool RELU, bool RES, bool F32OUT>
__global__ __launch_bounds__(256) void gemm_mfma16(
    const unsigned short* __restrict__ agg16,   // [N,128] fp16
    const unsigned short* __restrict__ h16self, // [N,128] fp16
    const unsigned short* __restrict__ res16,   // [N,128] fp16 residual
    const unsigned short* __restrict__ whp,     // packed fragment-order hi
    const unsigned short* __restrict__ wlp,     // packed fragment-order lo
    const float* __restrict__ bias,             // [128]
    float* __restrict__ hout,                   // [N,128] fp32 (F32OUT)
    unsigned short* __restrict__ h16out,        // [N,128] fp16 (!F32OUT)
    int N) {
    const int t = threadIdx.x;
    const int wv = t >> 6;
    const int lane = t & 63;
    const int r = lane & 15;
    const int q = lane >> 4;
    const int m0 = blockIdx.x * 128 + (wv >> 1) * 64;
    const int nhalf = wv & 1;                 // n0 = nhalf*64

    int rowA[4];
#pragma unroll
    for (int mt = 0; mt < 4; mt++) {
        int rr = m0 + mt * 16 + r;
        rowA[mt] = (rr < N) ? rr : (N - 1);   // clamp; clamped results discarded
    }

    // per-lane packed-W pointers; fragment (kb,nt) is at + ((nhalf*4+nt)*8+kb)*512
    const unsigned short* whL = whp + lane * 8;
    const unsigned short* wlL = wlp + lane * 8;

    f32x4 acc[4][4];
#pragma unroll
    for (int mt = 0; mt < 4; mt++)
#pragma unroll
        for (int nt = 0; nt < 4; nt++) acc[mt][nt] = (f32x4){0.f, 0.f, 0.f, 0.f};

    half8 aC[4], aN[4], whC[4], whN[4], wlC[4], wlN[4];

    // prologue: kb = 0
    {
        const int ko = q * 8;
#pragma unroll
        for (int mt = 0; mt < 4; mt++)
            aC[mt] = *(const half8*)(agg16 + (size_t)rowA[mt] * D + ko);
#pragma unroll
        for (int nt = 0; nt < 4; nt++) {
            const size_t wo = (size_t)(((nhalf * 4 + nt) * 8 + 0) << 9);
            whC[nt] = *(const half8*)(whL + wo);
            wlC[nt] = *(const half8*)(wlL + wo);
        }
    }

#pragma unroll
    for (int kb = 0; kb < 8; kb++) {
        if (kb < 7) {  // prefetch kb+1 (compile-time branch after unroll)
            const unsigned short* nbase = ((kb + 1) < 4) ? agg16 : h16self;
            const int ko = ((kb + 1) & 3) * 32 + q * 8;
#pragma unroll
            for (int mt = 0; mt < 4; mt++)
                aN[mt] = *(const half8*)(nbase + (size_t)rowA[mt] * D + ko);
#pragma unroll
            for (int nt = 0; nt < 4; nt++) {
                const size_t wo = (size_t)(((nhalf * 4 + nt) * 8 + (kb + 1)) << 9);
                whN[nt] = *(const half8*)(whL + wo);
                wlN[nt] = *(const half8*)(wlL + wo);
            }
        }
#pragma unroll
        for (int nt = 0; nt < 4; nt++) {
#pragma unroll
            for (int mt = 0; mt < 4; mt++) {
                acc[mt][nt] = __builtin_amdgcn_mfma_f32_16x16x32_f16(
                    aC[mt], whC[nt], acc[mt][nt], 0, 0, 0);
                acc[mt][nt] = __builtin_amdgcn_mfma_f32_16x16x32_f16(
                    aC[mt], wlC[nt], acc[mt][nt], 0, 0, 0);
            }
        }
        if (kb < 7) {  // rotate prefetch -> current
#pragma unroll
            for (int mt = 0; mt < 4; mt++) aC[mt] = aN[mt];
#pragma unroll
            for (int nt = 0; nt < 4; nt++) { whC[nt] = whN[nt]; wlC[nt] = wlN[nt]; }
        }
    }

    // epilogue: D col = nhalf*64 + nt*16 + r, row = m0 + mt*16 + q*4 + reg
#pragma unroll
    for (int nt = 0; nt < 4; nt++) {
        const int col = nhalf * 64 + nt * 16 + r;
        const float bv = bias[col];
#pragma unroll
        for (int mt = 0; mt < 4; mt++) {
#pragma unroll
            for (int reg = 0; reg < 4; reg++) {
                int row = m0 + mt * 16 + q * 4 + reg;
                if (row >= N) continue;
                float o = acc[mt][nt][reg] + bv;
                if (RES)
                    o += (float)(*(const _Float16*)(res16 + (size_t)row * D + col));
                if (RELU) o = fmaxf(o, 0.f);
                if (F32OUT) hout[(size_t)row * D + col] = o;
                else        h16out[(size_t)row * D + col] = f2h_bits(o);
            }
        }
    }
}

// ---------------------------------------------------------------------------
// logits[e] = dot(h[u], h[v])  (32 lanes per edge)
__global__ void decoder_kernel(const float* __restrict__ h,
                               const int* __restrict__ eli, int EL,
                               float* __restrict__ out) {
    long long tid = (long long)blockIdx.x * blockDim.x + threadIdx.x;
    int lane = (int)(tid & 31);
    long long e = tid >> 5;
    if (e >= EL) return;
    int u = eli[e];
    int v = eli[e + EL];
    float4 a = *(const float4*)(h + (long long)u * D + lane * 4);
    float4 b = *(const float4*)(h + (long long)v * D + lane * 4);
    float p = a.x * b.x + a.y * b.y + a.z * b.z + a.w * b.w;
#pragma unroll
    for (int off = 16; off; off >>= 1) p += __shfl_xor(p, off);
    if (lane == 0) out[e] = p;
}

// ---------------------------------------------------------------------------
static inline size_t align256(size_t x) { return (x + 255) & ~(size_t)255; }

extern "C" void kernel_launch(void* const* d_in, const int* in_sizes, int n_in,
                              void* d_out, int out_size, void* d_ws,
                              size_t ws_size, hipStream_t stream) {
    const float* x    = (const float*)d_in[0];   // [N, 128]
    const int*   ei   = (const int*)d_in[1];     // [2, E]
    const int*   eli  = (const int*)d_in[2];     // [2, EL]
    const float* wn   = (const float*)d_in[3];   // [3, 128, 128]
    const float* wsf  = (const float*)d_in[4];   // [3, 128, 128]
    const float* bias = (const float*)d_in[5];   // [3, 128]

    const int N  = in_sizes[0] / D;              // 100000
    const int E  = in_sizes[1] / 2;              // 1600000
    const int EL = in_sizes[2] / 2;              // 200000

    const int* src = ei;
    const int* dst = ei + E;

    // workspace layout (~160 MB)
    char* p = (char*)d_ws;
    int*   counts  = (int*)p;   p += align256((size_t)N * sizeof(int));  // hist, then countdown cursor
    int*   row_ptr = (int*)p;   p += align256((size_t)(N + 1) * sizeof(int));
    int*   bsum    = (int*)p;   p += align256((size_t)1024 * sizeof(int));
    unsigned short* whp = (unsigned short*)p; p += align256((size_t)3 * 32768 * 2);
    unsigned short* wlp = (unsigned short*)p; p += align256((size_t)3 * 32768 * 2);
    int*   csr_src = (int*)p;   p += align256((size_t)E * sizeof(int));
    unsigned short* x16   = (unsigned short*)p; p += align256((size_t)N * D * 2);
    unsigned short* h1    = (unsigned short*)p; p += align256((size_t)N * D * 2);
    unsigned short* h2    = (unsigned short*)p; p += align256((size_t)N * D * 2);
    unsigned short* agg16 = (unsigned short*)p; p += align256((size_t)N * D * 2);
    float* hA      = (float*)p;  // fp32 final (decoder input)

    const int nb = (N + 255) / 256;              // 391 (<= 512 for scan_small)
    const int eb = (E + 255) / 256;
    const int tile_blocks = (N + 127) / 128;     // 782
    const int gather_blocks = (N + 3) / 4;
    const int n8 = N * D / 8;

    // ---- weight prep (fragment-packed) + fp16 copy of x
    wprep_kernel<<<48, 256, 0, stream>>>(wn, wsf, whp, wlp);
    f32_to_f16<<<(n8 + 255) / 256, 256, 0, stream>>>(x, x16, n8);

    // ---- CSR build (once; reused by all 3 layers)
    hipMemsetAsync(counts, 0, (size_t)N * sizeof(int), stream);
    hist_kernel<<<eb, 256, 0, stream>>>(dst, E, counts);
    block_sum_kernel<<<nb, 256, 0, stream>>>(counts, N, bsum);
    scan_small_kernel<<<1, 512, 0, stream>>>(bsum, nb, row_ptr, N, E);
    block_scan_kernel<<<nb, 256, 0, stream>>>(counts, N, bsum, row_ptr);
    fill_kernel<<<eb, 256, 0, stream>>>(src, dst, E, row_ptr, counts, csr_src);

    // ---- layer 0: relu(conv(x)) -> h1 (fp16 only)
    gather_agg16<<<gather_blocks, 256, 0, stream>>>(x16, row_ptr, csr_src, agg16, N);
    gemm_mfma16<true, false, false><<<tile_blocks, 256, 0, stream>>>(
        agg16, x16, nullptr, whp + 0 * 32768, wlp + 0 * 32768, bias + 0 * D,
        nullptr, h1, N);

    // ---- layer 1: relu(conv(h1) + h1) -> h2 (fp16 only)
    gather_agg16<<<gather_blocks, 256, 0, stream>>>(h1, row_ptr, csr_src, agg16, N);
    gemm_mfma16<true, true, false><<<tile_blocks, 256, 0, stream>>>(
        agg16, h1, h1, whp + 1 * 32768, wlp + 1 * 32768, bias + 1 * D,
        nullptr, h2, N);

    // ---- layer 2: conv(h2) + h2 -> hA (fp32, decoder input)
    gather_agg16<<<gather_blocks, 256, 0, stream>>>(h2, row_ptr, csr_src, agg16, N);
    gemm_mfma16<false, true, true><<<tile_blocks, 256, 0, stream>>>(
        agg16, h2, h2, whp + 2 * 32768, wlp + 2 * 32768, bias + 2 * D,
        hA, nullptr, N);

    // ---- decoder
    decoder_kernel<<<(int)(((long long)EL * 32 + 255) / 256), 256, 0, stream>>>(
        hA, eli, EL, (float*)d_out);
}

// Round 13
// 595.891 us; speedup vs baseline: 2.0502x; 1.1056x over previous
//
#include <hip/hip_runtime.h>
#include <cstdint>
#include <cstddef>

#define D 128

typedef _Float16 half8 __attribute__((ext_vector_type(8)));
typedef float f32x4 __attribute__((ext_vector_type(4)));

static __device__ __forceinline__ unsigned short f2h_bits(float f) {
    union { _Float16 h; unsigned short u; } c;
    c.h = (_Float16)f;
    return c.u;
}

// ---------------------------------------------------------------------------
// Bucket-radix CSR build. Buckets of 256 nodes (b = dst >> 8), nbkt <= 512.
// k1: LDS-aggregated bucket histogram (2048 edges/block)
__global__ __launch_bounds__(256) void bucket_hist(
    const int* __restrict__ dst, int E, int nbkt, int* __restrict__ bcnt) {
    __shared__ int h[512];
    const int t = threadIdx.x;
    for (int i = t; i < nbkt; i += 256) h[i] = 0;
    __syncthreads();
    const int base = blockIdx.x * 2048;
#pragma unroll
    for (int j = 0; j < 8; j++) {
        int i = base + j * 256 + t;
        if (i < E) atomicAdd(&h[dst[i] >> 8], 1);
    }
    __syncthreads();
    for (int i = t; i < nbkt; i += 256)
        if (h[i]) atomicAdd(&bcnt[i], h[i]);
}

// k2: single-block exclusive scan of bucket counts -> bbase[0..nbkt]
__global__ void scan_buckets(const int* __restrict__ bcnt, int nbkt,
                             int* __restrict__ bbase,
                             int* __restrict__ row_ptr, int N, int E) {
    __shared__ int sh[512];
    int t = threadIdx.x;
    int v = (t < nbkt) ? bcnt[t] : 0;
    sh[t] = v;
    __syncthreads();
    for (int off = 1; off < 512; off <<= 1) {
        int add = (t >= off) ? sh[t - off] : 0;
        __syncthreads();
        sh[t] += add;
        __syncthreads();
    }
    if (t < nbkt) bbase[t] = sh[t] - v;   // exclusive
    if (t == 511) bbase[nbkt] = sh[511];  // total == E
    if (t == 0) row_ptr[N] = E;
}

// k3: scatter edges into bucket-major ebuf as packed 4B records.
// pack = src | (dst&255)<<24  (src < 2^17, so bits 17..23 are zero)
__global__ __launch_bounds__(256) void bucket_scatter(
    const int* __restrict__ src, const int* __restrict__ dst, int E, int nbkt,
    const int* __restrict__ bbase, int* __restrict__ bcur,
    unsigned* __restrict__ ebuf) {
    __shared__ int h[512];
    __shared__ int bo[512];
    const int t = threadIdx.x;
    for (int i = t; i < nbkt; i += 256) h[i] = 0;
    __syncthreads();
    const int base = blockIdx.x * 2048;
    unsigned pk[8]; int bk[8]; int rk[8];
#pragma unroll
    for (int j = 0; j < 8; j++) {
        int i = base + j * 256 + t;
        bk[j] = -1;
        if (i < E) {
            int d = dst[i];
            bk[j] = d >> 8;
            pk[j] = (unsigned)src[i] | ((unsigned)(d & 255) << 24);
            rk[j] = atomicAdd(&h[bk[j]], 1);
        }
    }
    __syncthreads();
    for (int i = t; i < nbkt; i += 256)
        bo[i] = h[i] ? atomicAdd(&bcur[i], h[i]) : 0;
    __syncthreads();
#pragma unroll
    for (int j = 0; j < 8; j++)
        if (bk[j] >= 0)
            ebuf[bbase[bk[j]] + bo[bk[j]] + rk[j]] = pk[j];
}

// k4: block b owns bucket b — local count+scan, writes row_ptr slice and
// fills its contiguous csr_src region (single-writer lines -> ~1x write amp).
__global__ __launch_bounds__(256) void bucket_fill(
    const unsigned* __restrict__ ebuf, const int* __restrict__ bbase,
    int* __restrict__ row_ptr, int* __restrict__ csr_src, int N) {
    __shared__ int cnt[256];
    __shared__ int sh[256];
    const int t = threadIdx.x;
    const int bkt = blockIdx.x;
    const int beg = bbase[bkt], end = bbase[bkt + 1];
    cnt[t] = 0;
    __syncthreads();
    for (int i = beg + t; i < end; i += 256)
        atomicAdd(&cnt[ebuf[i] >> 24], 1);
    __syncthreads();
    int v = cnt[t];
    sh[t] = v;
    __syncthreads();
    for (int off = 1; off < 256; off <<= 1) {
        int add = (t >= off) ? sh[t - off] : 0;
        __syncthreads();
        sh[t] += add;
        __syncthreads();
    }
    const int excl = sh[t] - v;
    const int node = bkt * 256 + t;
    if (node < N) row_ptr[node] = beg + excl;
    __syncthreads();
    cnt[t] = beg + excl;   // running cursor
    __syncthreads();
    for (int i = beg + t; i < end; i += 256) {
        unsigned p = ebuf[i];
        int pos = atomicAdd(&cnt[p >> 24], 1);
        csr_src[pos] = (int)(p & 0xFFFFFFu);
    }
}

// ---------------------------------------------------------------------------
// fp32 -> fp16 copy (8 elems/thread)
__global__ void f32_to_f16(const float* __restrict__ in,
                           unsigned short* __restrict__ out, int n8) {
    int i = blockIdx.x * 256 + threadIdx.x;
    if (i >= n8) return;
    float4 f0 = ((const float4*)in)[2 * i];
    float4 f1 = ((const float4*)in)[2 * i + 1];
    union { unsigned short u[8]; uint4 v; } o;
    o.u[0] = f2h_bits(f0.x); o.u[1] = f2h_bits(f0.y);
    o.u[2] = f2h_bits(f0.z); o.u[3] = f2h_bits(f0.w);
    o.u[4] = f2h_bits(f1.x); o.u[5] = f2h_bits(f1.y);
    o.u[6] = f2h_bits(f1.z); o.u[7] = f2h_bits(f1.w);
    ((uint4*)out)[i] = o.v;
}

// ---------------------------------------------------------------------------
// agg16[node] = fp16( (1/deg) * sum h16[csr_src[e]] )  (fp32 accumulation)
// one 64-lane wave per node, 2 fp16 (4 B) per lane, unroll 8
__global__ __launch_bounds__(256) void gather_agg16(
    const unsigned short* __restrict__ h16, const int* __restrict__ row_ptr,
    const int* __restrict__ csr_src,
    unsigned short* __restrict__ agg16, int N) {
    int node = (int)((blockIdx.x * (size_t)blockDim.x + threadIdx.x) >> 6);
    int lane = threadIdx.x & 63;
    if (node >= N) return;
    int beg = row_ptr[node], end = row_ptr[node + 1];
    const int col = lane * 2;
    float ax[8], ay[8];
#pragma unroll
    for (int j = 0; j < 8; j++) { ax[j] = 0.f; ay[j] = 0.f; }
    int e = beg;
    for (; e + 8 <= end; e += 8) {
        int s[8];
#pragma unroll
        for (int j = 0; j < 8; j++) s[j] = csr_src[e + j];
        unsigned int v[8];
#pragma unroll
        for (int j = 0; j < 8; j++)
            v[j] = *(const unsigned int*)(h16 + (size_t)s[j] * D + col);
#pragma unroll
        for (int j = 0; j < 8; j++) {
            union { unsigned int u; _Float16 h[2]; } c; c.u = v[j];
            ax[j] += (float)c.h[0];
            ay[j] += (float)c.h[1];
        }
    }
    for (; e < end; ++e) {
        int s = csr_src[e];
        union { unsigned int u; _Float16 h[2]; } c;
        c.u = *(const unsigned int*)(h16 + (size_t)s * D + col);
        ax[0] += (float)c.h[0];
        ay[0] += (float)c.h[1];
    }
    float sx = (ax[0] + ax[1]) + (ax[2] + ax[3]) + (ax[4] + ax[5]) + (ax[6] + ax[7]);
    float sy = (ay[0] + ay[1]) + (ay[2] + ay[3]) + (ay[4] + ay[5]) + (ay[6] + ay[7]);
    float sc = 1.0f / fmaxf((float)(end - beg), 1.0f);
    union { unsigned int u; _Float16 h[2]; } o;
    o.h[0] = (_Float16)(sx * sc);
    o.h[1] = (_Float16)(sy * sc);
    *(unsigned int*)(agg16 + (size_t)node * D + col) = o.u;
}

// ---------------------------------------------------------------------------
// Weight prep, FRAGMENT-PACKED (see R8 notes): one contiguous 1 KB wave-load
// per W fragment.
__global__ void wprep_kernel(const float* __restrict__ wn,
                             const float* __restrict__ wsf,
                             unsigned short* __restrict__ whp,
                             unsigned short* __restrict__ wlp) {
    int tid = blockIdx.x * 256 + threadIdx.x;   // [L][nb][kb][lane] = 12288
    if (tid >= 12288) return;
    int lane = tid & 63;
    int kb = (tid >> 6) & 7;
    int nb = (tid >> 9) & 7;
    int L  = tid >> 12;
    int n = nb * 16 + (lane & 15);
    int kbase = kb * 32 + (lane >> 4) * 8;
    union { unsigned short u[8]; uint4 v; } oh, ol;
#pragma unroll
    for (int j = 0; j < 8; j++) {
        int k = kbase + j;
        float w = (k < 128) ? wn[L * 16384 + k * 128 + n]
                            : wsf[L * 16384 + (k - 128) * 128 + n];
        _Float16 hi = (_Float16)w;
        _Float16 lo = (_Float16)(w - (float)hi);
        union { _Float16 h; unsigned short u; } ch, cl;
        ch.h = hi; cl.h = lo;
        oh.u[j] = ch.u;
        ol.u[j] = cl.u;
    }
    ((uint4*)whp)[tid] = oh.v;
    ((uint4*)wlp)[tid] = ol.v;
}

// ---------------------------------------------------------------------------
// fp16 MFMA GEMM, software-pipelined (1-ahead A/W prefetch), packed W.
// Block: 128 rows x 128 cols, 4 waves (2m x 2n), wave = 64m x 64n (mt=4,nt=4).
template <bool RELU, bool RES, bool F32OUT>
__global__ __launch_bounds__(256) void gemm_mfma16(
    const unsigned short* __restrict__ agg16,   // [N,128] fp16
    const unsigned short* __restrict__ h16self, // [N,128] fp16
    const unsigned short* __restrict__ res16,   // [N,128] fp16 residual
    const unsigned short* __restrict__ whp,     // packed fragment-order hi
    const unsigned short* __restrict__ wlp,     // packed fragment-order lo
    const float* __restrict__ bias,             // [128]
    float* __restrict__ hout,                   // [N,128] fp32 (F32OUT)
    unsigned short* __restrict__ h16out,        // [N,128] fp16 (!F32OUT)
    int N) {
    const int t = threadIdx.x;
    const int wv = t >> 6;
    const int lane = t & 63;
    const int r = lane & 15;
    const int q = lane >> 4;
    const int m0 = blockIdx.x * 128 + (wv >> 1) * 64;
    const int nhalf = wv & 1;                 // n0 = nhalf*64

    int rowA[4];
#pragma unroll
    for (int mt = 0; mt < 4; mt++) {
        int rr = m0 + mt * 16 + r;
        rowA[mt] = (rr < N) ? rr : (N - 1);   // clamp; clamped results discarded
    }

    const unsigned short* whL = whp + lane * 8;
    const unsigned short* wlL = wlp + lane * 8;

    f32x4 acc[4][4];
#pragma unroll
    for (int mt = 0; mt < 4; mt++)
#pragma unroll
        for (int nt = 0; nt < 4; nt++) acc[mt][nt] = (f32x4){0.f, 0.f, 0.f, 0.f};

    half8 aC[4], aN[4], whC[4], whN[4], wlC[4], wlN[4];

    // prologue: kb = 0
    {
        const int ko = q * 8;
#pragma unroll
        for (int mt = 0; mt < 4; mt++)
            aC[mt] = *(const half8*)(agg16 + (size_t)rowA[mt] * D + ko);
#pragma unroll
        for (int nt = 0; nt < 4; nt++) {
            const size_t wo = (size_t)(((nhalf * 4 + nt) * 8 + 0) << 9);
            whC[nt] = *(const half8*)(whL + wo);
            wlC[nt] = *(const half8*)(wlL + wo);
        }
    }

#pragma unroll
    for (int kb = 0; kb < 8; kb++) {
        if (kb < 7) {  // prefetch kb+1
            const unsigned short* nbase = ((kb + 1) < 4) ? agg16 : h16self;
            const int ko = ((kb + 1) & 3) * 32 + q * 8;
#pragma unroll
            for (int mt = 0; mt < 4; mt++)
                aN[mt] = *(const half8*)(nbase + (size_t)rowA[mt] * D + ko);
#pragma unroll
            for (int nt = 0; nt < 4; nt++) {
                const size_t wo = (size_t)(((nhalf * 4 + nt) * 8 + (kb + 1)) << 9);
                whN[nt] = *(const half8*)(whL + wo);
                wlN[nt] = *(const half8*)(wlL + wo);
            }
        }
#pragma unroll
        for (int nt = 0; nt < 4; nt++) {
#pragma unroll
            for (int mt = 0; mt < 4; mt++) {
                acc[mt][nt] = __builtin_amdgcn_mfma_f32_16x16x32_f16(
                    aC[mt], whC[nt], acc[mt][nt], 0, 0, 0);
                acc[mt][nt] = __builtin_amdgcn_mfma_f32_16x16x32_f16(
                    aC[mt], wlC[nt], acc[mt][nt], 0, 0, 0);
            }
        }
        if (kb < 7) {
#pragma unroll
            for (int mt = 0; mt < 4; mt++) aC[mt] = aN[mt];
#pragma unroll
            for (int nt = 0; nt < 4; nt++) { whC[nt] = whN[nt]; wlC[nt] = wlN[nt]; }
        }
    }

    // epilogue: D col = nhalf*64 + nt*16 + r, row = m0 + mt*16 + q*4 + reg
#pragma unroll
    for (int nt = 0; nt < 4; nt++) {
        const int col = nhalf * 64 + nt * 16 + r;
        const float bv = bias[col];
#pragma unroll
        for (int mt = 0; mt < 4; mt++) {
#pragma unroll
            for (int reg = 0; reg < 4; reg++) {
                int row = m0 + mt * 16 + q * 4 + reg;
                if (row >= N) continue;
                float o = acc[mt][nt][reg] + bv;
                if (RES)
                    o += (float)(*(const _Float16*)(res16 + (size_t)row * D + col));
                if (RELU) o = fmaxf(o, 0.f);
                if (F32OUT) hout[(size_t)row * D + col] = o;
                else        h16out[(size_t)row * D + col] = f2h_bits(o);
            }
        }
    }
}

// ---------------------------------------------------------------------------
// logits[e] = dot(h[u], h[v])  (32 lanes per edge)
__global__ void decoder_kernel(const float* __restrict__ h,
                               const int* __restrict__ eli, int EL,
                               float* __restrict__ out) {
    long long tid = (long long)blockIdx.x * blockDim.x + threadIdx.x;
    int lane = (int)(tid & 31);
    long long e = tid >> 5;
    if (e >= EL) return;
    int u = eli[e];
    int v = eli[e + EL];
    float4 a = *(const float4*)(h + (long long)u * D + lane * 4);
    float4 b = *(const float4*)(h + (long long)v * D + lane * 4);
    float p = a.x * b.x + a.y * b.y + a.z * b.z + a.w * b.w;
#pragma unroll
    for (int off = 16; off; off >>= 1) p += __shfl_xor(p, off);
    if (lane == 0) out[e] = p;
}

// ---------------------------------------------------------------------------
static inline size_t align256(size_t x) { return (x + 255) & ~(size_t)255; }

extern "C" void kernel_launch(void* const* d_in, const int* in_sizes, int n_in,
                              void* d_out, int out_size, void* d_ws,
                              size_t ws_size, hipStream_t stream) {
    const float* x    = (const float*)d_in[0];   // [N, 128]
    const int*   ei   = (const int*)d_in[1];     // [2, E]
    const int*   eli  = (const int*)d_in[2];     // [2, EL]
    const float* wn   = (const float*)d_in[3];   // [3, 128, 128]
    const float* wsf  = (const float*)d_in[4];   // [3, 128, 128]
    const float* bias = (const float*)d_in[5];   // [3, 128]

    const int N  = in_sizes[0] / D;              // 100000
    const int E  = in_sizes[1] / 2;              // 1600000
    const int EL = in_sizes[2] / 2;              // 200000

    const int* src = ei;
    const int* dst = ei + E;

    const int nbkt = (N + 255) / 256;            // 391 buckets (<= 512)

    // workspace layout (~170 MB)
    char* p = (char*)d_ws;
    int*   bcnt    = (int*)p;   p += align256((size_t)512 * sizeof(int));
    int*   bcur    = (int*)p;   p += align256((size_t)512 * sizeof(int));
    int*   bbase   = (int*)p;   p += align256((size_t)516 * sizeof(int));
    int*   row_ptr = (int*)p;   p += align256((size_t)(N + 1) * sizeof(int));
    unsigned short* whp = (unsigned short*)p; p += align256((size_t)3 * 32768 * 2);
    unsigned short* wlp = (unsigned short*)p; p += align256((size_t)3 * 32768 * 2);
    unsigned* ebuf = (unsigned*)p; p += align256((size_t)E * sizeof(unsigned));
    int*   csr_src = (int*)p;   p += align256((size_t)E * sizeof(int));
    unsigned short* x16   = (unsigned short*)p; p += align256((size_t)N * D * 2);
    unsigned short* h1    = (unsigned short*)p; p += align256((size_t)N * D * 2);
    unsigned short* h2    = (unsigned short*)p; p += align256((size_t)N * D * 2);
    unsigned short* agg16 = (unsigned short*)p; p += align256((size_t)N * D * 2);
    float* hA      = (float*)p;  // fp32 final (decoder input)

    const int eb2k = (E + 2047) / 2048;          // 782
    const int tile_blocks = (N + 127) / 128;     // 782
    const int gather_blocks = (N + 3) / 4;
    const int n8 = N * D / 8;

    // ---- weight prep (fragment-packed) + fp16 copy of x
    wprep_kernel<<<48, 256, 0, stream>>>(wn, wsf, whp, wlp);
    f32_to_f16<<<(n8 + 255) / 256, 256, 0, stream>>>(x, x16, n8);

    // ---- bucket-radix CSR build (once; reused by all 3 layers)
    hipMemsetAsync(bcnt, 0, (size_t)1024 * sizeof(int), stream);  // bcnt+bcur
    bucket_hist<<<eb2k, 256, 0, stream>>>(dst, E, nbkt, bcnt);
    scan_buckets<<<1, 512, 0, stream>>>(bcnt, nbkt, bbase, row_ptr, N, E);
    bucket_scatter<<<eb2k, 256, 0, stream>>>(src, dst, E, nbkt, bbase, bcur, ebuf);
    bucket_fill<<<nbkt, 256, 0, stream>>>(ebuf, bbase, row_ptr, csr_src, N);

    // ---- layer 0: relu(conv(x)) -> h1 (fp16 only)
    gather_agg16<<<gather_blocks, 256, 0, stream>>>(x16, row_ptr, csr_src, agg16, N);
    gemm_mfma16<true, false, false><<<tile_blocks, 256, 0, stream>>>(
        agg16, x16, nullptr, whp + 0 * 32768, wlp + 0 * 32768, bias + 0 * D,
        nullptr, h1, N);

    // ---- layer 1: relu(conv(h1) + h1) -> h2 (fp16 only)
    gather_agg16<<<gather_blocks, 256, 0, stream>>>(h1, row_ptr, csr_src, agg16, N);
    gemm_mfma16<true, true, false><<<tile_blocks, 256, 0, stream>>>(
        agg16, h1, h1, whp + 1 * 32768, wlp + 1 * 32768, bias + 1 * D,
        nullptr, h2, N);

    // ---- layer 2: conv(h2) + h2 -> hA (fp32, decoder input)
    gather_agg16<<<gather_blocks, 256, 0, stream>>>(h2, row_ptr, csr_src, agg16, N);
    gemm_mfma16<false, true, true><<<tile_blocks, 256, 0, stream>>>(
        agg16, h2, h2, whp + 2 * 32768, wlp + 2 * 32768, bias + 2 * D,
        hA, nullptr, N);

    // ---- decoder
    decoder_kernel<<<(int)(((long long)EL * 32 + 255) / 256), 256, 0, stream>>>(
        hA, eli, EL, (float*)d_out);
}